// Round 3
// baseline (790.840 us; speedup 1.0000x reference)
//
#include <hip/hip_runtime.h>

#define BB   16
#define SS   512
#define DD   1024
#define HH   16
#define DKK  64
#define DFFN 4096
#define LN_EPS 1e-6f

typedef __attribute__((ext_vector_type(8))) __bf16 bf16x8;
typedef __attribute__((ext_vector_type(4))) float f32x4;
typedef __attribute__((ext_vector_type(8))) unsigned short ushort8;
typedef __attribute__((ext_vector_type(4))) unsigned short ushort4_t;

#define AS1 __attribute__((address_space(1)))
#define AS3 __attribute__((address_space(3)))

__device__ __forceinline__ unsigned short f2bf(float f) {
  unsigned int u = __float_as_uint(f);
  u += 0x7FFFu + ((u >> 16) & 1u);   // round-nearest-even
  return (unsigned short)(u >> 16);
}
__device__ __forceinline__ float bf2f(unsigned short u) {
  return __uint_as_float(((unsigned int)u) << 16);
}

__device__ __forceinline__ float gelu_f(float x) {
  float x3 = x * x * x;
  return 0.5f * x * (1.0f + tanhf(0.7978845608028654f * (x + 0.044715f * x3)));
}

// ---------------- LayerNorm: fp32 in -> bf16 out (strided out)
__global__ __launch_bounds__(256) void ln_kernel(const float* __restrict__ x,
                                                 const float* __restrict__ g,
                                                 const float* __restrict__ b,
                                                 unsigned short* __restrict__ out, int ldo) {
  const int row = blockIdx.x;
  const int tid = threadIdx.x;
  const float* xr = x + (size_t)row * DD;
  float4 v = *(const float4*)(xr + tid * 4);
  float s = v.x + v.y + v.z + v.w;
#pragma unroll
  for (int off = 1; off < 64; off <<= 1) s += __shfl_xor(s, off);
  __shared__ float red[8];
  const int wid = tid >> 6, l = tid & 63;
  if (l == 0) red[wid] = s;
  __syncthreads();
  const float mean = (red[0] + red[1] + red[2] + red[3]) * (1.0f / DD);
  float4 d;
  d.x = v.x - mean; d.y = v.y - mean; d.z = v.z - mean; d.w = v.w - mean;
  float ss = d.x * d.x + d.y * d.y + d.z * d.z + d.w * d.w;
#pragma unroll
  for (int off = 1; off < 64; off <<= 1) ss += __shfl_xor(ss, off);
  if (l == 0) red[4 + wid] = ss;
  __syncthreads();
  const float var = (red[4] + red[5] + red[6] + red[7]) * (1.0f / (DD - 1));
  const float scale = 1.0f / (sqrtf(var) + LN_EPS);
  float4 gv = *(const float4*)(g + tid * 4);
  float4 bv = *(const float4*)(b + tid * 4);
  ushort4_t o;
  o[0] = f2bf(gv.x * d.x * scale + bv.x);
  o[1] = f2bf(gv.y * d.y * scale + bv.y);
  o[2] = f2bf(gv.z * d.z * scale + bv.z);
  o[3] = f2bf(gv.w * d.w * scale + bv.w);
  *(ushort4_t*)(out + (size_t)row * ldo + tid * 4) = o;
}

// ---------------- fp32 -> bf16, strided rows of DD elems
__global__ __launch_bounds__(256) void cvt_bf16(const float* __restrict__ in,
                                                unsigned short* __restrict__ out, int ldo) {
  const int i = blockIdx.x * 256 + threadIdx.x;  // i over MT*DD/8
  const int row = i >> 7;
  const int c0 = (i & 127) * 8;
  const float4* p = (const float4*)(in + (size_t)row * DD + c0);
  float4 a = p[0], b = p[1];
  ushort8 o;
  o[0] = f2bf(a.x); o[1] = f2bf(a.y); o[2] = f2bf(a.z); o[3] = f2bf(a.w);
  o[4] = f2bf(b.x); o[5] = f2bf(b.y); o[6] = f2bf(b.z); o[7] = f2bf(b.w);
  *(ushort8*)(out + (size_t)row * ldo + c0) = o;
}

// ---------------- W[K][N] fp32 -> WT[N][K] bf16 (strided out rows)
__global__ __launch_bounds__(256) void transpose_cvt(const float* __restrict__ W,
                                                     unsigned short* __restrict__ WT,
                                                     int N, int ldo) {
  __shared__ float tile[32][33];
  const int tx = threadIdx.x & 31, ty = threadIdx.x >> 5;  // ty 0..7
  const int n0 = blockIdx.x * 32, k0 = blockIdx.y * 32;
#pragma unroll
  for (int i = 0; i < 32; i += 8)
    tile[ty + i][tx] = W[(size_t)(k0 + ty + i) * N + n0 + tx];
  __syncthreads();
#pragma unroll
  for (int i = 0; i < 32; i += 8)
    WT[(size_t)(n0 + ty + i) * ldo + k0 + tx] = f2bf(tile[tx][ty + i]);
}

// ---------------- bias prep: qvb = concat(bq,bv) ; kcb = bk+bt
__global__ __launch_bounds__(256) void bias_prep(const float* __restrict__ bq,
                                                 const float* __restrict__ bv,
                                                 const float* __restrict__ bk,
                                                 const float* __restrict__ bt,
                                                 float* __restrict__ qvb,
                                                 float* __restrict__ kcb) {
  const int i = blockIdx.x * 256 + threadIdx.x;
  if (i < 2048) qvb[i] = (i < 1024) ? bq[i] : bv[i - 1024];
  else kcb[i - 2048] = bk[i - 2048] + bt[i - 2048];
}

// ---------------- mask int32 -> bitmask u64 (1 bit per key)
__global__ __launch_bounds__(256) void mask_pack(const int* __restrict__ mask,
                                                 unsigned long long* __restrict__ bits) {
  const int gid = blockIdx.x * 256 + threadIdx.x;
  const int m = mask[gid];
  const unsigned long long b = __ballot(m != 0);
  if ((threadIdx.x & 63) == 0) bits[gid >> 6] = b;
}

// ---------------- sigmoid(ml) -> bf16
__global__ __launch_bounds__(256) void sig_cvt(const float* __restrict__ ml,
                                               unsigned short* __restrict__ sg) {
  const int i = blockIdx.x * 256 + threadIdx.x;  // over S*S/8
  const float4* p = (const float4*)(ml + (size_t)i * 8);
  float4 a = p[0], b = p[1];
  ushort8 o;
  o[0] = f2bf(1.0f / (1.0f + __expf(-a.x)));
  o[1] = f2bf(1.0f / (1.0f + __expf(-a.y)));
  o[2] = f2bf(1.0f / (1.0f + __expf(-a.z)));
  o[3] = f2bf(1.0f / (1.0f + __expf(-a.w)));
  o[4] = f2bf(1.0f / (1.0f + __expf(-b.x)));
  o[5] = f2bf(1.0f / (1.0f + __expf(-b.y)));
  o[6] = f2bf(1.0f / (1.0f + __expf(-b.z)));
  o[7] = f2bf(1.0f / (1.0f + __expf(-b.w)));
  *(ushort8*)(sg + (size_t)i * 8) = o;
}

// ---------------- GEMM: C[M][N] = A[M][K](bf16,lda) @ BT[N][K](bf16)^T + bias
// EPI 0: -> bf16 ; EPI 1: +resid -> f32 ; EPI 2: gelu -> bf16
// EPI 3: cols<1024 -> bf16 Cout (ldc=1024) ; cols>=1024 -> transposed bf16 vTo[1024][8192]
#define GBM 128
#define GBN 128
#define GBK 64

template <int EPI>
__global__ __launch_bounds__(256) void gemm_bt(const unsigned short* __restrict__ A, int lda,
                                               const unsigned short* __restrict__ BT,
                                               const float* __restrict__ bias,
                                               const float* __restrict__ resid,
                                               void* __restrict__ Cout,
                                               unsigned short* __restrict__ vTo,
                                               int M, int N, int K) {
  __shared__ __align__(16) unsigned short smA[GBM * GBK];
  __shared__ __align__(16) unsigned short smB[GBN * GBK];
  const int tid = threadIdx.x;
  const int nb = N / GBN;
  // bijective XCD swizzle (all grids here are %8==0)
  const int nwg = gridDim.x;
  int bid = blockIdx.x;
  if ((nwg & 7) == 0) bid = (bid & 7) * (nwg >> 3) + (bid >> 3);
  const int mb = bid / nb;
  const int nbk = bid % nb;
  const int wid = tid >> 6, l = tid & 63;
  const int wr = wid >> 1, wc = wid & 1;
  const int lr = l & 15, lg = l >> 4;
  const int srow = tid >> 3;       // 0..31
  const int scol = (tid & 7) * 8;

  f32x4 acc[4][4] = {};
  const unsigned short* Abase = A + (size_t)mb * GBM * lda + (size_t)srow * lda + scol;
  const unsigned short* Bbase = BT + (size_t)nbk * GBN * K + (size_t)srow * K + scol;

  for (int kt = 0; kt < K; kt += GBK) {
#pragma unroll
    for (int c = 0; c < 4; ++c)
      __builtin_amdgcn_global_load_lds((const AS1 void*)(Abase + kt + (size_t)c * 32 * lda),
                                       (AS3 void*)(smA + c * 2048 + wid * 512), 16, 0, 0);
#pragma unroll
    for (int c = 0; c < 4; ++c)
      __builtin_amdgcn_global_load_lds((const AS1 void*)(Bbase + kt + (size_t)c * 32 * K),
                                       (AS3 void*)(smB + c * 2048 + wid * 512), 16, 0, 0);
    __syncthreads();
#pragma unroll
    for (int ks = 0; ks < 2; ++ks) {
      bf16x8 af[4], bfr[4];
#pragma unroll
      for (int mi = 0; mi < 4; ++mi)
        af[mi] = *(const bf16x8*)(smA + (wr * 64 + mi * 16 + lr) * GBK + ks * 32 + lg * 8);
#pragma unroll
      for (int ni = 0; ni < 4; ++ni)
        bfr[ni] = *(const bf16x8*)(smB + (wc * 64 + ni * 16 + lr) * GBK + ks * 32 + lg * 8);
#pragma unroll
      for (int mi = 0; mi < 4; ++mi)
#pragma unroll
        for (int ni = 0; ni < 4; ++ni)
          acc[mi][ni] = __builtin_amdgcn_mfma_f32_16x16x32_bf16(af[mi], bfr[ni], acc[mi][ni], 0, 0, 0);
    }
    __syncthreads();
  }

  const int colb = nbk * GBN + wc * 64;
  const int rowb = mb * GBM + wr * 64;
#pragma unroll
  for (int ni = 0; ni < 4; ++ni) {
    const int col = colb + ni * 16 + lr;
    const float bv = bias[col];
    if (EPI == 3 && colb >= 1024) {
      // transposed v write: vTo[(col-1024)][row], rows packed in ushort4
#pragma unroll
      for (int mi = 0; mi < 4; ++mi) {
        const int row0 = rowb + mi * 16 + lg * 4;
        ushort4_t t;
#pragma unroll
        for (int j = 0; j < 4; ++j) t[j] = f2bf(acc[mi][ni][j] + bv);
        *(ushort4_t*)(vTo + (size_t)(col - 1024) * 8192 + row0) = t;
      }
    } else {
#pragma unroll
      for (int mi = 0; mi < 4; ++mi) {
#pragma unroll
        for (int j = 0; j < 4; ++j) {
          const int row = rowb + mi * 16 + lg * 4 + j;
          float vv = acc[mi][ni][j] + bv;
          if (EPI == 2) vv = gelu_f(vv);
          if (EPI == 1) {
            const size_t o = (size_t)row * N + col;
            ((float*)Cout)[o] = vv + resid[o];
          } else if (EPI == 3) {
            ((unsigned short*)Cout)[(size_t)row * 1024 + col] = f2bf(vv);
          } else {
            ((unsigned short*)Cout)[(size_t)row * N + col] = f2bf(vv);
          }
        }
      }
    }
  }
}

// ---------------- Fused attention v3: block per (b,h,half), 8 waves, 8 q-tiles.
// kc combined; V^T from global (written by qv GEMM epilogue); no-max softmax;
// 2 barriers per q-tile; PV with 4 independent accumulator chains.
__global__ __launch_bounds__(512, 4) void attn2b(const unsigned short* __restrict__ qb,
                                                 const unsigned short* __restrict__ vT,
                                                 const unsigned short* __restrict__ kcb,
                                                 const unsigned long long* __restrict__ mbits,
                                                 const unsigned short* __restrict__ sg,
                                                 unsigned short* __restrict__ ctx) {
  __shared__ __align__(16) unsigned short Ps[32 * 512];  // [row][key] swizzled
  __shared__ float reds[32 * 8];

  const int tid = threadIdx.x;
  const int g = blockIdx.x & 1;
  const int h = (blockIdx.x >> 1) & (HH - 1);
  const int b = blockIdx.x >> 5;
  const int wid = tid >> 6, l = tid & 63;
  const int lr = l & 15, lg = l >> 4;

  const unsigned short* qg = qb + (size_t)b * SS * DD + h * DKK;
  const unsigned short* kg = kcb + (size_t)b * SS * DD + h * DKK;
  unsigned short* cg = ctx + (size_t)b * SS * DD + h * DKK;

  // kc B-fragments, one-time hoist. wave wid covers keys wid*64..+63
  bf16x8 kb[4][2];
#pragma unroll
  for (int ni = 0; ni < 4; ++ni)
#pragma unroll
    for (int ks = 0; ks < 2; ++ks)
      kb[ni][ks] = *(const bf16x8*)(kg + (size_t)(wid * 64 + ni * 16 + lr) * DD + ks * 32 + lg * 8);

  // PV output tile ownership: rows mo*16..+15, dk cols no*16..+15
  const int mo = wid >> 2, no = wid & 3;
  const unsigned short* vbase = vT + (size_t)(h * DKK + no * 16 + lr) * 8192 + b * SS;

  for (int qt = g * 8; qt < g * 8 + 8; ++qt) {
    const int q0 = qt * 32;
    bf16x8 af[2][2];
#pragma unroll
    for (int mi = 0; mi < 2; ++mi)
#pragma unroll
      for (int ks = 0; ks < 2; ++ks)
        af[mi][ks] = *(const bf16x8*)(qg + (size_t)(q0 + mi * 16 + lr) * DD + ks * 32 + lg * 8);

    f32x4 sc[2][4] = {};
#pragma unroll
    for (int ks = 0; ks < 2; ++ks)
#pragma unroll
      for (int mi = 0; mi < 2; ++mi)
#pragma unroll
        for (int ni = 0; ni < 4; ++ni)
          sc[mi][ni] = __builtin_amdgcn_mfma_f32_16x16x32_bf16(af[mi][ks], kb[ni][ks], sc[mi][ni], 0, 0, 0);

    // scale + mask + exp (no max subtraction: |scores| bounded ~3) + row sum
#pragma unroll
    for (int mi = 0; mi < 2; ++mi)
#pragma unroll
      for (int j = 0; j < 4; ++j) {
        const int rowg = q0 + mi * 16 + lg * 4 + j;
        const unsigned long long mw = mbits[((size_t)b * SS + rowg) * 8 + wid];
        float s = 0.f;
#pragma unroll
        for (int ni = 0; ni < 4; ++ni) {
          float t = sc[mi][ni][j] * 0.125f;
          t = ((mw >> (ni * 16 + lr)) & 1ull) ? t : -1e9f;
          const float p = __expf(t);
          sc[mi][ni][j] = p;
          s += p;
        }
        s += __shfl_xor(s, 1);
        s += __shfl_xor(s, 2);
        s += __shfl_xor(s, 4);
        s += __shfl_xor(s, 8);
        if (lr == 0) reds[(mi * 16 + lg * 4 + j) * 8 + wid] = s;
      }
    __syncthreads();

    // normalize * sigmoid, write P (swizzled)
#pragma unroll
    for (int mi = 0; mi < 2; ++mi)
#pragma unroll
      for (int j = 0; j < 4; ++j) {
        const int rl = mi * 16 + lg * 4 + j;
        const float* r = reds + rl * 8;
        const float sum = ((r[0] + r[1]) + (r[2] + r[3])) + ((r[4] + r[5]) + (r[6] + r[7]));
        const float rinv = 1.0f / fmaxf(sum, 1e-30f);
        const int rowg = q0 + rl;
        const int sw = (rl & 7) << 3;
#pragma unroll
        for (int ni = 0; ni < 4; ++ni) {
          const int col = wid * 64 + ni * 16 + lr;
          const float sig = bf2f(sg[(size_t)rowg * SS + col]);
          Ps[rl * 512 + (col ^ sw)] = f2bf(sc[mi][ni][j] * rinv * sig);
        }
      }
    __syncthreads();

    // PV: wave's 16x16 output tile, 4 independent MFMA chains over 512 keys
    f32x4 a0 = {}, a1 = {}, a2 = {}, a3 = {};
    const int prow = mo * 16 + lr;
    const int psw = (prow & 7) << 3;
#pragma unroll
    for (int kk = 0; kk < 16; kk += 4) {
      bf16x8 p0 = *(const bf16x8*)(Ps + prow * 512 + (((kk + 0) * 32 + lg * 8) ^ psw));
      bf16x8 p1 = *(const bf16x8*)(Ps + prow * 512 + (((kk + 1) * 32 + lg * 8) ^ psw));
      bf16x8 p2 = *(const bf16x8*)(Ps + prow * 512 + (((kk + 2) * 32 + lg * 8) ^ psw));
      bf16x8 p3 = *(const bf16x8*)(Ps + prow * 512 + (((kk + 3) * 32 + lg * 8) ^ psw));
      bf16x8 v0 = *(const bf16x8*)(vbase + (kk + 0) * 32 + lg * 8);
      bf16x8 v1 = *(const bf16x8*)(vbase + (kk + 1) * 32 + lg * 8);
      bf16x8 v2 = *(const bf16x8*)(vbase + (kk + 2) * 32 + lg * 8);
      bf16x8 v3 = *(const bf16x8*)(vbase + (kk + 3) * 32 + lg * 8);
      a0 = __builtin_amdgcn_mfma_f32_16x16x32_bf16(p0, v0, a0, 0, 0, 0);
      a1 = __builtin_amdgcn_mfma_f32_16x16x32_bf16(p1, v1, a1, 0, 0, 0);
      a2 = __builtin_amdgcn_mfma_f32_16x16x32_bf16(p2, v2, a2, 0, 0, 0);
      a3 = __builtin_amdgcn_mfma_f32_16x16x32_bf16(p3, v3, a3, 0, 0, 0);
    }
    const f32x4 accv = (a0 + a1) + (a2 + a3);
#pragma unroll
    for (int j = 0; j < 4; ++j)
      cg[(size_t)(q0 + mo * 16 + lg * 4 + j) * DD + no * 16 + lr] = f2bf(accv[j]);
    // Ps-reuse hazard vs next iteration's writes is covered by next sum-barrier
  }
}

// ----------------------------------------------------------------------------
extern "C" void kernel_launch(void* const* d_in, const int* in_sizes, int n_in,
                              void* d_out, int out_size, void* d_ws, size_t ws_size,
                              hipStream_t stream) {
  (void)in_sizes; (void)n_in; (void)out_size; (void)ws_size;
  const float* x    = (const float*)d_in[0];
  const float* timep= (const float*)d_in[1];
  const float* Wq = (const float*)d_in[2];  const float* bq = (const float*)d_in[3];
  const float* Wk = (const float*)d_in[4];  const float* bk = (const float*)d_in[5];
  const float* Wt = (const float*)d_in[6];  const float* bt = (const float*)d_in[7];
  const float* Wv = (const float*)d_in[8];  const float* bv = (const float*)d_in[9];
  const float* Wo = (const float*)d_in[10]; const float* bo = (const float*)d_in[11];
  const float* W1 = (const float*)d_in[12]; const float* b1 = (const float*)d_in[13];
  const float* W2 = (const float*)d_in[14]; const float* b2 = (const float*)d_in[15];
  const float* ln1g = (const float*)d_in[16]; const float* ln1b = (const float*)d_in[17];
  const float* ln2g = (const float*)d_in[18]; const float* ln2b = (const float*)d_in[19];
  const float* ml   = (const float*)d_in[20];
  const int*   mask = (const int*)d_in[21];
  float* out = (float*)d_out;

  char* w = (char*)d_ws;
  auto alloc = [&](size_t sz) { char* p = w; w += (sz + 255) & ~(size_t)255; return p; };
  const int MT = BB * SS;  // 8192 rows

  unsigned short* WqvT = (unsigned short*)alloc((size_t)2048 * 1024 * 2);  // [2048][1024]
  unsigned short* WkcT = (unsigned short*)alloc((size_t)1024 * 2048 * 2);  // [1024][2048]
  unsigned short* WoT  = (unsigned short*)alloc((size_t)DD * DD * 2);
  unsigned short* W1T  = (unsigned short*)alloc((size_t)DD * DFFN * 2);    // [DFFN][DD]
  unsigned short* W2T  = (unsigned short*)alloc((size_t)DFFN * DD * 2);    // [DD][DFFN]
  float* qvb = (float*)alloc(2048 * 4);
  float* kcbias = (float*)alloc(1024 * 4);
  unsigned long long* mbits = (unsigned long long*)alloc((size_t)BB * SS * 8 * 8);
  unsigned short* sg  = (unsigned short*)alloc((size_t)SS * SS * 2);
  unsigned short* xt2 = (unsigned short*)alloc((size_t)MT * 2048 * 2);  // [xn | time]
  unsigned short* qbuf = (unsigned short*)alloc((size_t)MT * DD * 2);   // q [8192][1024]
  unsigned short* vTb = (unsigned short*)alloc((size_t)DD * MT * 2);    // v^T [1024][8192]
  unsigned short* kcb = (unsigned short*)alloc((size_t)MT * DD * 2);    // k1+k2
  float*          x2  = (float*)alloc((size_t)MT * DD * 4);
  unsigned short* hb  = (unsigned short*)alloc((size_t)MT * DFFN * 2);
  unsigned short* ctx = xt2;          // xt2 dead after qv+kc GEMMs
  unsigned short* xn2 = xt2;          // ctx dead after Wo GEMM

  // weight prep
  transpose_cvt<<<dim3(32, 32), 256, 0, stream>>>(Wq, WqvT, 1024, 1024);
  transpose_cvt<<<dim3(32, 32), 256, 0, stream>>>(Wv, WqvT + (size_t)1024 * 1024, 1024, 1024);
  transpose_cvt<<<dim3(32, 32), 256, 0, stream>>>(Wk, WkcT, 1024, 2048);
  transpose_cvt<<<dim3(32, 32), 256, 0, stream>>>(Wt, WkcT + 1024, 1024, 2048);
  transpose_cvt<<<dim3(32, 32), 256, 0, stream>>>(Wo, WoT, 1024, 1024);
  transpose_cvt<<<dim3(128, 32), 256, 0, stream>>>(W1, W1T, 4096, 1024);
  transpose_cvt<<<dim3(32, 128), 256, 0, stream>>>(W2, W2T, 1024, 4096);
  bias_prep<<<dim3(12), 256, 0, stream>>>(bq, bv, bk, bt, qvb, kcbias);
  mask_pack<<<dim3(BB * SS * SS / 256), 256, 0, stream>>>(mask, mbits);
  sig_cvt<<<dim3(SS * SS / 8 / 256), 256, 0, stream>>>(ml, sg);

  // xt2 = [ln1(x) | bf16(time)]
  ln_kernel<<<dim3(MT), 256, 0, stream>>>(x, ln1g, ln1b, xt2, 2048);
  cvt_bf16<<<dim3(MT * DD / 8 / 256), 256, 0, stream>>>(timep, xt2 + 1024, 2048);

  // projections: qv (N=2048,K=1024, q->qbuf, v->vT) ; kc (N=1024,K=2048)
  gemm_bt<3><<<dim3((MT / GBM) * (2048 / GBN)), 256, 0, stream>>>(xt2, 2048, WqvT, qvb, nullptr, (void*)qbuf, vTb, MT, 2048, 1024);
  gemm_bt<0><<<dim3((MT / GBM) * (1024 / GBN)), 256, 0, stream>>>(xt2, 2048, WkcT, kcbias, nullptr, (void*)kcb, nullptr, MT, 1024, 2048);

  attn2b<<<dim3(BB * HH * 2), 512, 0, stream>>>(qbuf, vTb, kcb, mbits, sg, ctx);

  gemm_bt<1><<<dim3((MT / GBM) * (1024 / GBN)), 256, 0, stream>>>(ctx, 1024, WoT, bo, x, (void*)x2, nullptr, MT, 1024, 1024);
  ln_kernel<<<dim3(MT), 256, 0, stream>>>(x2, ln2g, ln2b, xn2, 1024);
  gemm_bt<2><<<dim3((MT / GBM) * (DFFN / GBN)), 256, 0, stream>>>(xn2, 1024, W1T, b1, nullptr, (void*)hb, nullptr, MT, DFFN, 1024);
  gemm_bt<1><<<dim3((MT / GBM) * (1024 / GBN)), 256, 0, stream>>>(hb, 4096, W2T, b2, x2, (void*)out, nullptr, MT, 1024, DFFN);
}

// Round 4
// 615.359 us; speedup vs baseline: 1.2852x; 1.2852x over previous
//
#include <hip/hip_runtime.h>

#define BB   16
#define SS   512
#define DD   1024
#define HH   16
#define DKK  64
#define DFFN 4096
#define LN_EPS 1e-6f

typedef __attribute__((ext_vector_type(8))) __bf16 bf16x8;
typedef __attribute__((ext_vector_type(4))) float f32x4;
typedef __attribute__((ext_vector_type(8))) unsigned short ushort8;
typedef __attribute__((ext_vector_type(4))) unsigned short ushort4_t;

#define AS1 __attribute__((address_space(1)))
#define AS3 __attribute__((address_space(3)))

__device__ __forceinline__ unsigned short f2bf(float f) {
  unsigned int u = __float_as_uint(f);
  u += 0x7FFFu + ((u >> 16) & 1u);   // round-nearest-even
  return (unsigned short)(u >> 16);
}
__device__ __forceinline__ float bf2f(unsigned short u) {
  return __uint_as_float(((unsigned int)u) << 16);
}

__device__ __forceinline__ float gelu_f(float x) {
  float x3 = x * x * x;
  return 0.5f * x * (1.0f + tanhf(0.7978845608028654f * (x + 0.044715f * x3)));
}

// ---------------- LayerNorm: fp32 in -> bf16 out (strided out)
__global__ __launch_bounds__(256) void ln_kernel(const float* __restrict__ x,
                                                 const float* __restrict__ g,
                                                 const float* __restrict__ b,
                                                 unsigned short* __restrict__ out, int ldo) {
  const int row = blockIdx.x;
  const int tid = threadIdx.x;
  const float* xr = x + (size_t)row * DD;
  float4 v = *(const float4*)(xr + tid * 4);
  float s = v.x + v.y + v.z + v.w;
#pragma unroll
  for (int off = 1; off < 64; off <<= 1) s += __shfl_xor(s, off);
  __shared__ float red[8];
  const int wid = tid >> 6, l = tid & 63;
  if (l == 0) red[wid] = s;
  __syncthreads();
  const float mean = (red[0] + red[1] + red[2] + red[3]) * (1.0f / DD);
  float4 d;
  d.x = v.x - mean; d.y = v.y - mean; d.z = v.z - mean; d.w = v.w - mean;
  float ss = d.x * d.x + d.y * d.y + d.z * d.z + d.w * d.w;
#pragma unroll
  for (int off = 1; off < 64; off <<= 1) ss += __shfl_xor(ss, off);
  if (l == 0) red[4 + wid] = ss;
  __syncthreads();
  const float var = (red[4] + red[5] + red[6] + red[7]) * (1.0f / (DD - 1));
  const float scale = 1.0f / (sqrtf(var) + LN_EPS);
  float4 gv = *(const float4*)(g + tid * 4);
  float4 bv = *(const float4*)(b + tid * 4);
  ushort4_t o;
  o[0] = f2bf(gv.x * d.x * scale + bv.x);
  o[1] = f2bf(gv.y * d.y * scale + bv.y);
  o[2] = f2bf(gv.z * d.z * scale + bv.z);
  o[3] = f2bf(gv.w * d.w * scale + bv.w);
  *(ushort4_t*)(out + (size_t)row * ldo + tid * 4) = o;
}

// ---------------- fp32 -> bf16, strided rows of DD elems
__global__ __launch_bounds__(256) void cvt_bf16(const float* __restrict__ in,
                                                unsigned short* __restrict__ out, int ldo) {
  const int i = blockIdx.x * 256 + threadIdx.x;  // i over MT*DD/8
  const int row = i >> 7;
  const int c0 = (i & 127) * 8;
  const float4* p = (const float4*)(in + (size_t)row * DD + c0);
  float4 a = p[0], b = p[1];
  ushort8 o;
  o[0] = f2bf(a.x); o[1] = f2bf(a.y); o[2] = f2bf(a.z); o[3] = f2bf(a.w);
  o[4] = f2bf(b.x); o[5] = f2bf(b.y); o[6] = f2bf(b.z); o[7] = f2bf(b.w);
  *(ushort8*)(out + (size_t)row * ldo + c0) = o;
}

// ---------------- W[K][N] fp32 -> WT[N][K] bf16 (strided out rows)
__global__ __launch_bounds__(256) void transpose_cvt(const float* __restrict__ W,
                                                     unsigned short* __restrict__ WT,
                                                     int N, int ldo) {
  __shared__ float tile[32][33];
  const int tx = threadIdx.x & 31, ty = threadIdx.x >> 5;  // ty 0..7
  const int n0 = blockIdx.x * 32, k0 = blockIdx.y * 32;
#pragma unroll
  for (int i = 0; i < 32; i += 8)
    tile[ty + i][tx] = W[(size_t)(k0 + ty + i) * N + n0 + tx];
  __syncthreads();
#pragma unroll
  for (int i = 0; i < 32; i += 8)
    WT[(size_t)(n0 + ty + i) * ldo + k0 + tx] = f2bf(tile[tx][ty + i]);
}

// ---------------- bias prep: qvb = concat(bq,bv) ; kcb = bk+bt
__global__ __launch_bounds__(256) void bias_prep(const float* __restrict__ bq,
                                                 const float* __restrict__ bv,
                                                 const float* __restrict__ bk,
                                                 const float* __restrict__ bt,
                                                 float* __restrict__ qvb,
                                                 float* __restrict__ kcb) {
  const int i = blockIdx.x * 256 + threadIdx.x;
  if (i < 2048) qvb[i] = (i < 1024) ? bq[i] : bv[i - 1024];
  else kcb[i - 2048] = bk[i - 2048] + bt[i - 2048];
}

// ---------------- mask int32 -> bitmask u64 (1 bit per key)
__global__ __launch_bounds__(256) void mask_pack(const int* __restrict__ mask,
                                                 unsigned long long* __restrict__ bits) {
  const int gid = blockIdx.x * 256 + threadIdx.x;
  const int m = mask[gid];
  const unsigned long long b = __ballot(m != 0);
  if ((threadIdx.x & 63) == 0) bits[gid >> 6] = b;
}

// ---------------- sigmoid(ml) -> bf16
__global__ __launch_bounds__(256) void sig_cvt(const float* __restrict__ ml,
                                               unsigned short* __restrict__ sg) {
  const int i = blockIdx.x * 256 + threadIdx.x;  // over S*S/8
  const float4* p = (const float4*)(ml + (size_t)i * 8);
  float4 a = p[0], b = p[1];
  ushort8 o;
  o[0] = f2bf(1.0f / (1.0f + __expf(-a.x)));
  o[1] = f2bf(1.0f / (1.0f + __expf(-a.y)));
  o[2] = f2bf(1.0f / (1.0f + __expf(-a.z)));
  o[3] = f2bf(1.0f / (1.0f + __expf(-a.w)));
  o[4] = f2bf(1.0f / (1.0f + __expf(-b.x)));
  o[5] = f2bf(1.0f / (1.0f + __expf(-b.y)));
  o[6] = f2bf(1.0f / (1.0f + __expf(-b.z)));
  o[7] = f2bf(1.0f / (1.0f + __expf(-b.w)));
  *(ushort8*)(sg + (size_t)i * 8) = o;
}

// ---------------- GEMM: C[M][N] = A[M][K](bf16,lda) @ BT[N][K](bf16)^T + bias
// EPI 0: -> bf16 ; EPI 1: +resid -> f32 ; EPI 2: gelu -> bf16
// EPI 3: cols<1024 -> bf16 Cout (ldc=1024) ; cols>=1024 -> transposed bf16 vTo[1024][8192]
#define GBM 128
#define GBN 128
#define GBK 64

template <int EPI>
__global__ __launch_bounds__(256) void gemm_bt(const unsigned short* __restrict__ A, int lda,
                                               const unsigned short* __restrict__ BT,
                                               const float* __restrict__ bias,
                                               const float* __restrict__ resid,
                                               void* __restrict__ Cout,
                                               unsigned short* __restrict__ vTo,
                                               int M, int N, int K) {
  __shared__ __align__(16) unsigned short smA[GBM * GBK];
  __shared__ __align__(16) unsigned short smB[GBN * GBK];
  const int tid = threadIdx.x;
  const int nb = N / GBN;
  // bijective XCD swizzle (all grids here are %8==0)
  const int nwg = gridDim.x;
  int bid = blockIdx.x;
  if ((nwg & 7) == 0) bid = (bid & 7) * (nwg >> 3) + (bid >> 3);
  const int mb = bid / nb;
  const int nbk = bid % nb;
  const int wid = tid >> 6, l = tid & 63;
  const int wr = wid >> 1, wc = wid & 1;
  const int lr = l & 15, lg = l >> 4;
  const int srow = tid >> 3;       // 0..31
  const int scol = (tid & 7) * 8;

  f32x4 acc[4][4] = {};
  const unsigned short* Abase = A + (size_t)mb * GBM * lda + (size_t)srow * lda + scol;
  const unsigned short* Bbase = BT + (size_t)nbk * GBN * K + (size_t)srow * K + scol;

  for (int kt = 0; kt < K; kt += GBK) {
#pragma unroll
    for (int c = 0; c < 4; ++c)
      __builtin_amdgcn_global_load_lds((const AS1 void*)(Abase + kt + (size_t)c * 32 * lda),
                                       (AS3 void*)(smA + c * 2048 + wid * 512), 16, 0, 0);
#pragma unroll
    for (int c = 0; c < 4; ++c)
      __builtin_amdgcn_global_load_lds((const AS1 void*)(Bbase + kt + (size_t)c * 32 * K),
                                       (AS3 void*)(smB + c * 2048 + wid * 512), 16, 0, 0);
    __syncthreads();
#pragma unroll
    for (int ks = 0; ks < 2; ++ks) {
      bf16x8 af[4], bfr[4];
#pragma unroll
      for (int mi = 0; mi < 4; ++mi)
        af[mi] = *(const bf16x8*)(smA + (wr * 64 + mi * 16 + lr) * GBK + ks * 32 + lg * 8);
#pragma unroll
      for (int ni = 0; ni < 4; ++ni)
        bfr[ni] = *(const bf16x8*)(smB + (wc * 64 + ni * 16 + lr) * GBK + ks * 32 + lg * 8);
#pragma unroll
      for (int mi = 0; mi < 4; ++mi)
#pragma unroll
        for (int ni = 0; ni < 4; ++ni)
          acc[mi][ni] = __builtin_amdgcn_mfma_f32_16x16x32_bf16(af[mi], bfr[ni], acc[mi][ni], 0, 0, 0);
    }
    __syncthreads();
  }

  const int colb = nbk * GBN + wc * 64;
  const int rowb = mb * GBM + wr * 64;
#pragma unroll
  for (int ni = 0; ni < 4; ++ni) {
    const int col = colb + ni * 16 + lr;
    const float bv = bias[col];
    if (EPI == 3 && colb >= 1024) {
      // transposed v write: vTo[(col-1024)][row], rows packed in ushort4
#pragma unroll
      for (int mi = 0; mi < 4; ++mi) {
        const int row0 = rowb + mi * 16 + lg * 4;
        ushort4_t t;
#pragma unroll
        for (int j = 0; j < 4; ++j) t[j] = f2bf(acc[mi][ni][j] + bv);
        *(ushort4_t*)(vTo + (size_t)(col - 1024) * 8192 + row0) = t;
      }
    } else {
#pragma unroll
      for (int mi = 0; mi < 4; ++mi) {
#pragma unroll
        for (int j = 0; j < 4; ++j) {
          const int row = rowb + mi * 16 + lg * 4 + j;
          float vv = acc[mi][ni][j] + bv;
          if (EPI == 2) vv = gelu_f(vv);
          if (EPI == 1) {
            const size_t o = (size_t)row * N + col;
            ((float*)Cout)[o] = vv + resid[o];
          } else if (EPI == 3) {
            ((unsigned short*)Cout)[(size_t)row * 1024 + col] = f2bf(vv);
          } else {
            ((unsigned short*)Cout)[(size_t)row * N + col] = f2bf(vv);
          }
        }
      }
    }
  }
}

// ---------------- Fused attention v4: flash-style. Block = (b,h,qt32), 4 waves.
// 8 key-tiles of 64; QK^T from global KC frags; no-max exp; unnormalized
// P*sig -> 4KB dbuf swizzled LDS (1 barrier/kt); PV from global V^T frags;
// end normalization. XCD-chunk swizzle co-locates the 16 qt-blocks of a
// (b,h) on one XCD so KC/V^T (128 KB) are L2-hits after first touch.
__global__ __launch_bounds__(256) void attn3(const unsigned short* __restrict__ qb,
                                             const unsigned short* __restrict__ vT,
                                             const unsigned short* __restrict__ kcb,
                                             const unsigned long long* __restrict__ mbits,
                                             const unsigned short* __restrict__ sg,
                                             unsigned short* __restrict__ ctx) {
  __shared__ __align__(16) unsigned short Plds[2][32 * 64];
  __shared__ float red[4 * 32];

  const int tid = threadIdx.x;
  const int w = tid >> 6, l = tid & 63;
  const int lr = l & 15, lg = l >> 4;
  // inverse round-robin: blocks with bid%8==c land on XCD c and get 512
  // consecutive virtual ids -> all 16 qt of a (b,h) share an XCD.
  const int virt = (blockIdx.x & 7) * 512 + (blockIdx.x >> 3);
  const int qt = virt & 15;
  const int h = (virt >> 4) & 15;
  const int b = virt >> 8;
  const int q0 = qt * 32;

  const unsigned short* qg = qb + (size_t)b * SS * DD + h * DKK;
  const unsigned short* kg = kcb + (size_t)b * SS * DD + h * DKK;
  const unsigned short* vg = vT + (size_t)(h * DKK + w * 16 + lr) * 8192 + b * SS;
  unsigned short* cg = ctx + (size_t)b * SS * DD + h * DKK;

  // Q A-fragments (one-time): rows q0+mi*16+lr, k = ks*32+lg*8
  bf16x8 qf[2][2];
#pragma unroll
  for (int mi = 0; mi < 2; ++mi)
#pragma unroll
    for (int ks = 0; ks < 2; ++ks)
      qf[mi][ks] = *(const bf16x8*)(qg + (size_t)(q0 + mi * 16 + lr) * DD + ks * 32 + lg * 8);

  f32x4 oa0[2] = {}, oa1[2] = {};   // PV accum (rows mi*16+lg*4+j, dk=w*16+lr)
  float ssum[2][4] = {};

  for (int kt = 0; kt < 8; ++kt) {
    const int key = kt * 64 + w * 16 + lr;
    bf16x8 kf[2];
#pragma unroll
    for (int ks = 0; ks < 2; ++ks)
      kf[ks] = *(const bf16x8*)(kg + (size_t)key * DD + ks * 32 + lg * 8);

    f32x4 sc[2] = {};
#pragma unroll
    for (int ks = 0; ks < 2; ++ks)
#pragma unroll
      for (int mi = 0; mi < 2; ++mi)
        sc[mi] = __builtin_amdgcn_mfma_f32_16x16x32_bf16(qf[mi][ks], kf[ks], sc[mi], 0, 0, 0);

    // no-max softmax numerator: p = exp(s/8) (masked->0), pw = p*sigmoid
    unsigned short* Pb = Plds[kt & 1];
#pragma unroll
    for (int mi = 0; mi < 2; ++mi)
#pragma unroll
      for (int j = 0; j < 4; ++j) {
        const int rowg = q0 + mi * 16 + lg * 4 + j;
        const unsigned long long mw = mbits[((size_t)b * SS + rowg) * 8 + kt];
        float t = sc[mi][j] * 0.125f;
        t = ((mw >> (w * 16 + lr)) & 1ull) ? t : -1e9f;
        const float p = __expf(t);
        ssum[mi][j] += p;
        const float sig = bf2f(sg[(size_t)rowg * SS + key]);
        const int row = mi * 16 + lg * 4 + j;
        Pb[row * 64 + ((w * 16 + lr) ^ ((row & 7) * 8))] = f2bf(p * sig);
      }
    __syncthreads();

    // PV: A = P frag (rows mi*16+lr), B = V^T frag (dk=w*16+lr)
#pragma unroll
    for (int mi = 0; mi < 2; ++mi) {
      bf16x8 v0 = *(const bf16x8*)(vg + kt * 64 + 0 * 32 + lg * 8);
      bf16x8 v1 = *(const bf16x8*)(vg + kt * 64 + 1 * 32 + lg * 8);
      bf16x8 p0 = *(const bf16x8*)(Pb + (mi * 16 + lr) * 64 + ((0 * 32 + lg * 8) ^ ((lr & 7) * 8)));
      bf16x8 p1 = *(const bf16x8*)(Pb + (mi * 16 + lr) * 64 + ((1 * 32 + lg * 8) ^ ((lr & 7) * 8)));
      oa0[mi] = __builtin_amdgcn_mfma_f32_16x16x32_bf16(p0, v0, oa0[mi], 0, 0, 0);
      oa1[mi] = __builtin_amdgcn_mfma_f32_16x16x32_bf16(p1, v1, oa1[mi], 0, 0, 0);
    }
  }

  // combine per-wave row-sum partials (each wave summed its own 16-key slices)
#pragma unroll
  for (int mi = 0; mi < 2; ++mi)
#pragma unroll
    for (int j = 0; j < 4; ++j) {
      float s = ssum[mi][j];
      s += __shfl_xor(s, 1);
      s += __shfl_xor(s, 2);
      s += __shfl_xor(s, 4);
      s += __shfl_xor(s, 8);
      if (lr == 0) red[w * 32 + mi * 16 + lg * 4 + j] = s;
    }
  __syncthreads();
#pragma unroll
  for (int mi = 0; mi < 2; ++mi) {
    const f32x4 oacc = oa0[mi] + oa1[mi];
#pragma unroll
    for (int j = 0; j < 4; ++j) {
      const int row = mi * 16 + lg * 4 + j;
      const float rs = ((red[row] + red[32 + row]) + (red[64 + row] + red[96 + row]));
      const float inv = 1.0f / fmaxf(rs, 1e-30f);
      cg[(size_t)(q0 + row) * DD + w * 16 + lr] = f2bf(oacc[j] * inv);
    }
  }
}

// ----------------------------------------------------------------------------
extern "C" void kernel_launch(void* const* d_in, const int* in_sizes, int n_in,
                              void* d_out, int out_size, void* d_ws, size_t ws_size,
                              hipStream_t stream) {
  (void)in_sizes; (void)n_in; (void)out_size; (void)ws_size;
  const float* x    = (const float*)d_in[0];
  const float* timep= (const float*)d_in[1];
  const float* Wq = (const float*)d_in[2];  const float* bq = (const float*)d_in[3];
  const float* Wk = (const float*)d_in[4];  const float* bk = (const float*)d_in[5];
  const float* Wt = (const float*)d_in[6];  const float* bt = (const float*)d_in[7];
  const float* Wv = (const float*)d_in[8];  const float* bv = (const float*)d_in[9];
  const float* Wo = (const float*)d_in[10]; const float* bo = (const float*)d_in[11];
  const float* W1 = (const float*)d_in[12]; const float* b1 = (const float*)d_in[13];
  const float* W2 = (const float*)d_in[14]; const float* b2 = (const float*)d_in[15];
  const float* ln1g = (const float*)d_in[16]; const float* ln1b = (const float*)d_in[17];
  const float* ln2g = (const float*)d_in[18]; const float* ln2b = (const float*)d_in[19];
  const float* ml   = (const float*)d_in[20];
  const int*   mask = (const int*)d_in[21];
  float* out = (float*)d_out;

  char* w = (char*)d_ws;
  auto alloc = [&](size_t sz) { char* p = w; w += (sz + 255) & ~(size_t)255; return p; };
  const int MT = BB * SS;  // 8192 rows

  unsigned short* WqvT = (unsigned short*)alloc((size_t)2048 * 1024 * 2);  // [2048][1024]
  unsigned short* WkcT = (unsigned short*)alloc((size_t)1024 * 2048 * 2);  // [1024][2048]
  unsigned short* WoT  = (unsigned short*)alloc((size_t)DD * DD * 2);
  unsigned short* W1T  = (unsigned short*)alloc((size_t)DD * DFFN * 2);    // [DFFN][DD]
  unsigned short* W2T  = (unsigned short*)alloc((size_t)DFFN * DD * 2);    // [DD][DFFN]
  float* qvb = (float*)alloc(2048 * 4);
  float* kcbias = (float*)alloc(1024 * 4);
  unsigned long long* mbits = (unsigned long long*)alloc((size_t)BB * SS * 8 * 8);
  unsigned short* sg  = (unsigned short*)alloc((size_t)SS * SS * 2);
  unsigned short* xt2 = (unsigned short*)alloc((size_t)MT * 2048 * 2);  // [xn | time]
  unsigned short* qbuf = (unsigned short*)alloc((size_t)MT * DD * 2);   // q [8192][1024]
  unsigned short* vTb = (unsigned short*)alloc((size_t)DD * MT * 2);    // v^T [1024][8192]
  unsigned short* kcb = (unsigned short*)alloc((size_t)MT * DD * 2);    // k1+k2
  float*          x2  = (float*)alloc((size_t)MT * DD * 4);
  unsigned short* hb  = (unsigned short*)alloc((size_t)MT * DFFN * 2);
  unsigned short* ctx = xt2;          // xt2 dead after qv+kc GEMMs
  unsigned short* xn2 = xt2;          // ctx dead after Wo GEMM

  // weight prep
  transpose_cvt<<<dim3(32, 32), 256, 0, stream>>>(Wq, WqvT, 1024, 1024);
  transpose_cvt<<<dim3(32, 32), 256, 0, stream>>>(Wv, WqvT + (size_t)1024 * 1024, 1024, 1024);
  transpose_cvt<<<dim3(32, 32), 256, 0, stream>>>(Wk, WkcT, 1024, 2048);
  transpose_cvt<<<dim3(32, 32), 256, 0, stream>>>(Wt, WkcT + 1024, 1024, 2048);
  transpose_cvt<<<dim3(32, 32), 256, 0, stream>>>(Wo, WoT, 1024, 1024);
  transpose_cvt<<<dim3(128, 32), 256, 0, stream>>>(W1, W1T, 4096, 1024);
  transpose_cvt<<<dim3(32, 128), 256, 0, stream>>>(W2, W2T, 1024, 4096);
  bias_prep<<<dim3(12), 256, 0, stream>>>(bq, bv, bk, bt, qvb, kcbias);
  mask_pack<<<dim3(BB * SS * SS / 256), 256, 0, stream>>>(mask, mbits);
  sig_cvt<<<dim3(SS * SS / 8 / 256), 256, 0, stream>>>(ml, sg);

  // xt2 = [ln1(x) | bf16(time)]
  ln_kernel<<<dim3(MT), 256, 0, stream>>>(x, ln1g, ln1b, xt2, 2048);
  cvt_bf16<<<dim3(MT * DD / 8 / 256), 256, 0, stream>>>(timep, xt2 + 1024, 2048);

  // projections: qv (N=2048,K=1024, q->qbuf, v->vT) ; kc (N=1024,K=2048)
  gemm_bt<3><<<dim3((MT / GBM) * (2048 / GBN)), 256, 0, stream>>>(xt2, 2048, WqvT, qvb, nullptr, (void*)qbuf, vTb, MT, 2048, 1024);
  gemm_bt<0><<<dim3((MT / GBM) * (1024 / GBN)), 256, 0, stream>>>(xt2, 2048, WkcT, kcbias, nullptr, (void*)kcb, nullptr, MT, 1024, 2048);

  attn3<<<dim3(BB * HH * 16), 256, 0, stream>>>(qbuf, vTb, kcb, mbits, sg, ctx);

  gemm_bt<1><<<dim3((MT / GBM) * (1024 / GBN)), 256, 0, stream>>>(ctx, 1024, WoT, bo, x, (void*)x2, nullptr, MT, 1024, 1024);
  ln_kernel<<<dim3(MT), 256, 0, stream>>>(x2, ln2g, ln2b, xn2, 1024);
  gemm_bt<2><<<dim3((MT / GBM) * (DFFN / GBN)), 256, 0, stream>>>(xn2, 1024, W1T, b1, nullptr, (void*)hb, nullptr, MT, DFFN, 1024);
  gemm_bt<1><<<dim3((MT / GBM) * (1024 / GBN)), 256, 0, stream>>>(hb, 4096, W2T, b2, x2, (void*)out, nullptr, MT, 1024, DFFN);
}

// Round 5
// 535.576 us; speedup vs baseline: 1.4766x; 1.1490x over previous
//
#include <hip/hip_runtime.h>

#define BB   16
#define SS   512
#define DD   1024
#define HH   16
#define DKK  64
#define DFFN 4096
#define LN_EPS 1e-6f

typedef __attribute__((ext_vector_type(8))) __bf16 bf16x8;
typedef __attribute__((ext_vector_type(4))) float f32x4;
typedef __attribute__((ext_vector_type(8))) unsigned short ushort8;
typedef __attribute__((ext_vector_type(4))) unsigned short ushort4_t;

#define AS1 __attribute__((address_space(1)))
#define AS3 __attribute__((address_space(3)))

__device__ __forceinline__ unsigned short f2bf(float f) {
  unsigned int u = __float_as_uint(f);
  u += 0x7FFFu + ((u >> 16) & 1u);   // round-nearest-even
  return (unsigned short)(u >> 16);
}
__device__ __forceinline__ float bf2f(unsigned short u) {
  return __uint_as_float(((unsigned int)u) << 16);
}

__device__ __forceinline__ float gelu_f(float x) {
  float x3 = x * x * x;
  return 0.5f * x * (1.0f + tanhf(0.7978845608028654f * (x + 0.044715f * x3)));
}

__device__ __forceinline__ void sbar() {
  __builtin_amdgcn_sched_barrier(0);
  __builtin_amdgcn_s_barrier();
  __builtin_amdgcn_sched_barrier(0);
}
#define WAITVM(N)                                         \
  do {                                                    \
    __builtin_amdgcn_sched_barrier(0);                    \
    asm volatile("s_waitcnt vmcnt(" #N ")" ::: "memory"); \
    __builtin_amdgcn_sched_barrier(0);                    \
  } while (0)

// ---------------- LayerNorm: fp32 in -> bf16 out (strided out)
__global__ __launch_bounds__(256) void ln_kernel(const float* __restrict__ x,
                                                 const float* __restrict__ g,
                                                 const float* __restrict__ b,
                                                 unsigned short* __restrict__ out, int ldo) {
  const int row = blockIdx.x;
  const int tid = threadIdx.x;
  const float* xr = x + (size_t)row * DD;
  float4 v = *(const float4*)(xr + tid * 4);
  float s = v.x + v.y + v.z + v.w;
#pragma unroll
  for (int off = 1; off < 64; off <<= 1) s += __shfl_xor(s, off);
  __shared__ float red[8];
  const int wid = tid >> 6, l = tid & 63;
  if (l == 0) red[wid] = s;
  __syncthreads();
  const float mean = (red[0] + red[1] + red[2] + red[3]) * (1.0f / DD);
  float4 d;
  d.x = v.x - mean; d.y = v.y - mean; d.z = v.z - mean; d.w = v.w - mean;
  float ss = d.x * d.x + d.y * d.y + d.z * d.z + d.w * d.w;
#pragma unroll
  for (int off = 1; off < 64; off <<= 1) ss += __shfl_xor(ss, off);
  if (l == 0) red[4 + wid] = ss;
  __syncthreads();
  const float var = (red[4] + red[5] + red[6] + red[7]) * (1.0f / (DD - 1));
  const float scale = 1.0f / (sqrtf(var) + LN_EPS);
  float4 gv = *(const float4*)(g + tid * 4);
  float4 bv = *(const float4*)(b + tid * 4);
  ushort4_t o;
  o[0] = f2bf(gv.x * d.x * scale + bv.x);
  o[1] = f2bf(gv.y * d.y * scale + bv.y);
  o[2] = f2bf(gv.z * d.z * scale + bv.z);
  o[3] = f2bf(gv.w * d.w * scale + bv.w);
  *(ushort4_t*)(out + (size_t)row * ldo + tid * 4) = o;
}

// ---------------- fp32 -> bf16, strided rows of DD elems
__global__ __launch_bounds__(256) void cvt_bf16(const float* __restrict__ in,
                                                unsigned short* __restrict__ out, int ldo) {
  const int i = blockIdx.x * 256 + threadIdx.x;  // i over MT*DD/8
  const int row = i >> 7;
  const int c0 = (i & 127) * 8;
  const float4* p = (const float4*)(in + (size_t)row * DD + c0);
  float4 a = p[0], b = p[1];
  ushort8 o;
  o[0] = f2bf(a.x); o[1] = f2bf(a.y); o[2] = f2bf(a.z); o[3] = f2bf(a.w);
  o[4] = f2bf(b.x); o[5] = f2bf(b.y); o[6] = f2bf(b.z); o[7] = f2bf(b.w);
  *(ushort8*)(out + (size_t)row * ldo + c0) = o;
}

// ---------------- W[K][N] fp32 -> WT[N][K] bf16 (strided out rows)
__global__ __launch_bounds__(256) void transpose_cvt(const float* __restrict__ W,
                                                     unsigned short* __restrict__ WT,
                                                     int N, int ldo) {
  __shared__ float tile[32][33];
  const int tx = threadIdx.x & 31, ty = threadIdx.x >> 5;  // ty 0..7
  const int n0 = blockIdx.x * 32, k0 = blockIdx.y * 32;
#pragma unroll
  for (int i = 0; i < 32; i += 8)
    tile[ty + i][tx] = W[(size_t)(k0 + ty + i) * N + n0 + tx];
  __syncthreads();
#pragma unroll
  for (int i = 0; i < 32; i += 8)
    WT[(size_t)(n0 + ty + i) * ldo + k0 + tx] = f2bf(tile[tx][ty + i]);
}

// ---------------- bias prep: qvb = concat(bq,bv) ; kcb = bk+bt
__global__ __launch_bounds__(256) void bias_prep(const float* __restrict__ bq,
                                                 const float* __restrict__ bv,
                                                 const float* __restrict__ bk,
                                                 const float* __restrict__ bt,
                                                 float* __restrict__ qvb,
                                                 float* __restrict__ kcb) {
  const int i = blockIdx.x * 256 + threadIdx.x;
  if (i < 2048) qvb[i] = (i < 1024) ? bq[i] : bv[i - 1024];
  else kcb[i - 2048] = bk[i - 2048] + bt[i - 2048];
}

// ---------------- mask int32 -> bitmask u64 (1 bit per key)
__global__ __launch_bounds__(256) void mask_pack(const int* __restrict__ mask,
                                                 unsigned long long* __restrict__ bits) {
  const int gid = blockIdx.x * 256 + threadIdx.x;
  const int m = mask[gid];
  const unsigned long long b = __ballot(m != 0);
  if ((threadIdx.x & 63) == 0) bits[gid >> 6] = b;
}

// ---------------- sigmoid(ml) -> bf16
__global__ __launch_bounds__(256) void sig_cvt(const float* __restrict__ ml,
                                               unsigned short* __restrict__ sg) {
  const int i = blockIdx.x * 256 + threadIdx.x;  // over S*S/8
  const float4* p = (const float4*)(ml + (size_t)i * 8);
  float4 a = p[0], b = p[1];
  ushort8 o;
  o[0] = f2bf(1.0f / (1.0f + __expf(-a.x)));
  o[1] = f2bf(1.0f / (1.0f + __expf(-a.y)));
  o[2] = f2bf(1.0f / (1.0f + __expf(-a.z)));
  o[3] = f2bf(1.0f / (1.0f + __expf(-a.w)));
  o[4] = f2bf(1.0f / (1.0f + __expf(-b.x)));
  o[5] = f2bf(1.0f / (1.0f + __expf(-b.y)));
  o[6] = f2bf(1.0f / (1.0f + __expf(-b.z)));
  o[7] = f2bf(1.0f / (1.0f + __expf(-b.w)));
  *(ushort8*)(sg + (size_t)i * 8) = o;
}

// ---------------- 8-phase pipelined GEMM: C[M][N] = A[M][K] @ BT[N][K]^T + bias
// BM in {256,128}, BN=256, BK=64, 512 threads (2x4 waves).
// LDS st_16x32 swizzle via inverse-swizzled global source (linear gload_lds dest).
// Counted vmcnt (never 0); double-buffered; K-halves are the stage/free unit.
// EPI 0: -> bf16 ; EPI 1: +resid -> f32 ; EPI 2: gelu -> bf16
// EPI 3: cols<1024 -> bf16 q (ldc 1024) ; cols>=1024 -> transposed vTo[1024][8192]
template <int BM, int EPI>
__global__ __launch_bounds__(512, 2) void gemm8p(const unsigned short* __restrict__ A, int lda,
                                                 const unsigned short* __restrict__ BT,
                                                 const float* __restrict__ bias,
                                                 const float* __restrict__ resid,
                                                 void* __restrict__ Cout,
                                                 unsigned short* __restrict__ vTo,
                                                 int M, int N, int K) {
  constexpr int MI = BM / 32;      // A frags per wave: 8 / 4
  constexpr int ASUB = BM / 16;    // A subtiles per k-half
  constexpr int AHALF = BM * 32;   // elems per A k-half
  constexpr int ABUF = BM * 64;    // elems per A tile buffer
  constexpr int ACALL = BM / 128;  // 8KB stage calls per A k-half: 2 / 1

  __shared__ __align__(16) unsigned short smA[2 * ABUF];
  __shared__ __align__(16) unsigned short smB[2 * 16384];

  const int tid = threadIdx.x;
  const int w = tid >> 6, lane = tid & 63;
  const int lr = lane & 15, lg = lane >> 4;
  const int wr = w >> 2, wn = w & 3;

  const int nb = N / 256;
  const int nwg = gridDim.x;
  int bid = blockIdx.x;
  bid = (bid & 7) * (nwg >> 3) + (bid >> 3);  // all grids %8==0
  const int mb = bid / nb, nbk = bid % nb;

  // inverse-swizzle source mapping (involution): lds byte within 1KB subtile
  // o = lane*16 ; swz flips byte-bit5 when bit9 set
  const int uo = (lane * 16) ^ (lane & 32);
  const int srow = uo >> 6;          // row within 16-row subtile
  const int scol = (uo & 63) >> 1;   // element col within 32-col half (0,8,16,24)

  const unsigned short* pA[2];
  const unsigned short* pB[2];
#pragma unroll
  for (int j = 0; j < ACALL; ++j)
    pA[j] = A + (size_t)(mb * BM + (j * 8 + w) * 16 + srow) * lda + scol;
  if (ACALL == 1) pA[1] = pA[0];
#pragma unroll
  for (int j = 0; j < 2; ++j)
    pB[j] = BT + (size_t)(nbk * 256 + (j * 8 + w) * 16 + srow) * K + scol;

  auto stA = [&](int kt, int ks, int j, int d) {
    __builtin_amdgcn_global_load_lds(
        (const AS1 void*)(pA[j] + (size_t)kt * 64 + ks * 32),
        (AS3 void*)(smA + d * ABUF + ks * AHALF + j * 4096 + w * 512), 16, 0, 0);
  };
  auto stB = [&](int kt, int ks, int j, int d) {
    __builtin_amdgcn_global_load_lds(
        (const AS1 void*)(pB[j] + (size_t)kt * 64 + ks * 32),
        (AS3 void*)(smB + d * 16384 + ks * 8192 + j * 4096 + w * 512), 16, 0, 0);
  };

  // swizzled fragment read offset (elements) within a subtile row-group
  const int aoff = lr * 32 + ((lg * 8) ^ ((lr & 8) << 1));

  f32x4 acc[MI][4] = {};
  const int NT = K >> 6;

  // ---- prologue: tile 0 into buf 0 (k0 group first)
#pragma unroll
  for (int j = 0; j < ACALL; ++j) stA(0, 0, j, 0);
  stB(0, 0, 0, 0); stB(0, 0, 1, 0);
#pragma unroll
  for (int j = 0; j < ACALL; ++j) stA(0, 1, j, 0);
  stB(0, 1, 0, 0); stB(0, 1, 1, 0);
  if constexpr (ACALL == 2) { WAITVM(4); } else { WAITVM(3); }
  sbar();

  for (int kt = 0; kt < NT; ++kt) {
    const unsigned short* aD = smA + (kt & 1) * ABUF;
    const unsigned short* bD = smB + (kt & 1) * 16384;
    const int dn = (kt & 1) ^ 1;
    const bool nx = (kt + 1 < NT);
    bf16x8 af[4], bf[4];

    // ---- phase (ks=0, mh=0): read B(ks0)+A(mi 0..3, ks0); stage A-k0(t+1)
#pragma unroll
    for (int i = 0; i < 4; ++i)
      bf[i] = *(const bf16x8*)(bD + (wn * 4 + i) * 512 + aoff);
#pragma unroll
    for (int i = 0; i < 4; ++i)
      af[i] = *(const bf16x8*)(aD + (wr * MI + i) * 512 + aoff);
    if (nx) {
#pragma unroll
      for (int j = 0; j < ACALL; ++j) stA(kt + 1, 0, j, dn);
      if constexpr (ACALL == 1) { stB(kt + 1, 0, 0, dn); stB(kt + 1, 0, 1, dn); }
    }
    if constexpr (ACALL == 1) { WAITVM(3); }
    sbar();
    __builtin_amdgcn_s_setprio(1);
#pragma unroll
    for (int mi = 0; mi < 4; ++mi)
#pragma unroll
      for (int ni = 0; ni < 4; ++ni)
        acc[mi][ni] = __builtin_amdgcn_mfma_f32_16x16x32_bf16(af[mi], bf[ni], acc[mi][ni], 0, 0, 0);
    __builtin_amdgcn_s_setprio(0);
    sbar();

    if constexpr (ACALL == 2) {
      // ---- phase (0,1): A mi 4..7 ks0 (B reused); stage B-k0(t+1); vmcnt
#pragma unroll
      for (int i = 0; i < 4; ++i)
        af[i] = *(const bf16x8*)(aD + (wr * MI + 4 + i) * 512 + aoff);
      if (nx) { stB(kt + 1, 0, 0, dn); stB(kt + 1, 0, 1, dn); }
      WAITVM(4);
      sbar();
      __builtin_amdgcn_s_setprio(1);
#pragma unroll
      for (int mi = 0; mi < 4; ++mi)
#pragma unroll
        for (int ni = 0; ni < 4; ++ni)
          acc[4 + mi][ni] = __builtin_amdgcn_mfma_f32_16x16x32_bf16(af[mi], bf[ni], acc[4 + mi][ni], 0, 0, 0);
      __builtin_amdgcn_s_setprio(0);
      sbar();
    }

    // ---- phase (1,0): read B(ks1)+A(mi 0..3, ks1); stage A-k1(t+1)
#pragma unroll
    for (int i = 0; i < 4; ++i)
      bf[i] = *(const bf16x8*)(bD + (16 + wn * 4 + i) * 512 + aoff);
#pragma unroll
    for (int i = 0; i < 4; ++i)
      af[i] = *(const bf16x8*)(aD + (ASUB + wr * MI + i) * 512 + aoff);
    if (nx) {
#pragma unroll
      for (int j = 0; j < ACALL; ++j) stA(kt + 1, 1, j, dn);
      if constexpr (ACALL == 1) { stB(kt + 1, 1, 0, dn); stB(kt + 1, 1, 1, dn); }
    }
    if constexpr (ACALL == 1) { WAITVM(3); }
    sbar();
    __builtin_amdgcn_s_setprio(1);
#pragma unroll
    for (int mi = 0; mi < 4; ++mi)
#pragma unroll
      for (int ni = 0; ni < 4; ++ni)
        acc[mi][ni] = __builtin_amdgcn_mfma_f32_16x16x32_bf16(af[mi], bf[ni], acc[mi][ni], 0, 0, 0);
    __builtin_amdgcn_s_setprio(0);
    sbar();

    if constexpr (ACALL == 2) {
      // ---- phase (1,1): A mi 4..7 ks1; stage B-k1(t+1); vmcnt
#pragma unroll
      for (int i = 0; i < 4; ++i)
        af[i] = *(const bf16x8*)(aD + (ASUB + wr * MI + 4 + i) * 512 + aoff);
      if (nx) { stB(kt + 1, 1, 0, dn); stB(kt + 1, 1, 1, dn); }
      WAITVM(4);
      sbar();
      __builtin_amdgcn_s_setprio(1);
#pragma unroll
      for (int mi = 0; mi < 4; ++mi)
#pragma unroll
        for (int ni = 0; ni < 4; ++ni)
          acc[4 + mi][ni] = __builtin_amdgcn_mfma_f32_16x16x32_bf16(af[mi], bf[ni], acc[4 + mi][ni], 0, 0, 0);
      __builtin_amdgcn_s_setprio(0);
      sbar();
    }
  }

  // ---- epilogue
  const int colb = nbk * 256 + wn * 64;
  const int rowb = mb * BM + wr * (BM / 2);
#pragma unroll
  for (int ni = 0; ni < 4; ++ni) {
    const int col = colb + ni * 16 + lr;
    const float bv = bias[col];
    if (EPI == 3 && (colb + ni * 16) >= 1024) {
#pragma unroll
      for (int mi = 0; mi < MI; ++mi) {
        const int row0 = rowb + mi * 16 + lg * 4;
        ushort4_t t;
#pragma unroll
        for (int j = 0; j < 4; ++j) t[j] = f2bf(acc[mi][ni][j] + bv);
        *(ushort4_t*)(vTo + (size_t)(col - 1024) * 8192 + row0) = t;
      }
    } else {
#pragma unroll
      for (int mi = 0; mi < MI; ++mi) {
#pragma unroll
        for (int j = 0; j < 4; ++j) {
          const int row = rowb + mi * 16 + lg * 4 + j;
          float vv = acc[mi][ni][j] + bv;
          if (EPI == 2) vv = gelu_f(vv);
          if (EPI == 1) {
            const size_t o = (size_t)row * N + col;
            ((float*)Cout)[o] = vv + resid[o];
          } else if (EPI == 3) {
            ((unsigned short*)Cout)[(size_t)row * 1024 + col] = f2bf(vv);
          } else {
            ((unsigned short*)Cout)[(size_t)row * N + col] = f2bf(vv);
          }
        }
      }
    }
  }
}

// ---------------- Fused attention v4 (unchanged from round 4)
__global__ __launch_bounds__(256) void attn3(const unsigned short* __restrict__ qb,
                                             const unsigned short* __restrict__ vT,
                                             const unsigned short* __restrict__ kcb,
                                             const unsigned long long* __restrict__ mbits,
                                             const unsigned short* __restrict__ sg,
                                             unsigned short* __restrict__ ctx) {
  __shared__ __align__(16) unsigned short Plds[2][32 * 64];
  __shared__ float red[4 * 32];

  const int tid = threadIdx.x;
  const int w = tid >> 6, l = tid & 63;
  const int lr = l & 15, lg = l >> 4;
  const int virt = (blockIdx.x & 7) * 512 + (blockIdx.x >> 3);
  const int qt = virt & 15;
  const int h = (virt >> 4) & 15;
  const int b = virt >> 8;
  const int q0 = qt * 32;

  const unsigned short* qg = qb + (size_t)b * SS * DD + h * DKK;
  const unsigned short* kg = kcb + (size_t)b * SS * DD + h * DKK;
  const unsigned short* vg = vT + (size_t)(h * DKK + w * 16 + lr) * 8192 + b * SS;
  unsigned short* cg = ctx + (size_t)b * SS * DD + h * DKK;

  bf16x8 qf[2][2];
#pragma unroll
  for (int mi = 0; mi < 2; ++mi)
#pragma unroll
    for (int ks = 0; ks < 2; ++ks)
      qf[mi][ks] = *(const bf16x8*)(qg + (size_t)(q0 + mi * 16 + lr) * DD + ks * 32 + lg * 8);

  f32x4 oa0[2] = {}, oa1[2] = {};
  float ssum[2][4] = {};

  for (int kt = 0; kt < 8; ++kt) {
    const int key = kt * 64 + w * 16 + lr;
    bf16x8 kf[2];
#pragma unroll
    for (int ks = 0; ks < 2; ++ks)
      kf[ks] = *(const bf16x8*)(kg + (size_t)key * DD + ks * 32 + lg * 8);

    f32x4 sc[2] = {};
#pragma unroll
    for (int ks = 0; ks < 2; ++ks)
#pragma unroll
      for (int mi = 0; mi < 2; ++mi)
        sc[mi] = __builtin_amdgcn_mfma_f32_16x16x32_bf16(qf[mi][ks], kf[ks], sc[mi], 0, 0, 0);

    unsigned short* Pb = Plds[kt & 1];
#pragma unroll
    for (int mi = 0; mi < 2; ++mi)
#pragma unroll
      for (int j = 0; j < 4; ++j) {
        const int rowg = q0 + mi * 16 + lg * 4 + j;
        const unsigned long long mw = mbits[((size_t)b * SS + rowg) * 8 + kt];
        float t = sc[mi][j] * 0.125f;
        t = ((mw >> (w * 16 + lr)) & 1ull) ? t : -1e9f;
        const float p = __expf(t);
        ssum[mi][j] += p;
        const float sig = bf2f(sg[(size_t)rowg * SS + key]);
        const int row = mi * 16 + lg * 4 + j;
        Pb[row * 64 + ((w * 16 + lr) ^ ((row & 7) * 8))] = f2bf(p * sig);
      }
    __syncthreads();

#pragma unroll
    for (int mi = 0; mi < 2; ++mi) {
      bf16x8 v0 = *(const bf16x8*)(vg + kt * 64 + 0 * 32 + lg * 8);
      bf16x8 v1 = *(const bf16x8*)(vg + kt * 64 + 1 * 32 + lg * 8);
      bf16x8 p0 = *(const bf16x8*)(Pb + (mi * 16 + lr) * 64 + ((0 * 32 + lg * 8) ^ ((lr & 7) * 8)));
      bf16x8 p1 = *(const bf16x8*)(Pb + (mi * 16 + lr) * 64 + ((1 * 32 + lg * 8) ^ ((lr & 7) * 8)));
      oa0[mi] = __builtin_amdgcn_mfma_f32_16x16x32_bf16(p0, v0, oa0[mi], 0, 0, 0);
      oa1[mi] = __builtin_amdgcn_mfma_f32_16x16x32_bf16(p1, v1, oa1[mi], 0, 0, 0);
    }
  }

#pragma unroll
  for (int mi = 0; mi < 2; ++mi)
#pragma unroll
    for (int j = 0; j < 4; ++j) {
      float s = ssum[mi][j];
      s += __shfl_xor(s, 1);
      s += __shfl_xor(s, 2);
      s += __shfl_xor(s, 4);
      s += __shfl_xor(s, 8);
      if (lr == 0) red[w * 32 + mi * 16 + lg * 4 + j] = s;
    }
  __syncthreads();
#pragma unroll
  for (int mi = 0; mi < 2; ++mi) {
    const f32x4 oacc = oa0[mi] + oa1[mi];
#pragma unroll
    for (int j = 0; j < 4; ++j) {
      const int row = mi * 16 + lg * 4 + j;
      const float rs = ((red[row] + red[32 + row]) + (red[64 + row] + red[96 + row]));
      const float inv = 1.0f / fmaxf(rs, 1e-30f);
      cg[(size_t)(q0 + row) * DD + w * 16 + lr] = f2bf(oacc[j] * inv);
    }
  }
}

// ----------------------------------------------------------------------------
extern "C" void kernel_launch(void* const* d_in, const int* in_sizes, int n_in,
                              void* d_out, int out_size, void* d_ws, size_t ws_size,
                              hipStream_t stream) {
  (void)in_sizes; (void)n_in; (void)out_size; (void)ws_size;
  const float* x    = (const float*)d_in[0];
  const float* timep= (const float*)d_in[1];
  const float* Wq = (const float*)d_in[2];  const float* bq = (const float*)d_in[3];
  const float* Wk = (const float*)d_in[4];  const float* bk = (const float*)d_in[5];
  const float* Wt = (const float*)d_in[6];  const float* bt = (const float*)d_in[7];
  const float* Wv = (const float*)d_in[8];  const float* bv = (const float*)d_in[9];
  const float* Wo = (const float*)d_in[10]; const float* bo = (const float*)d_in[11];
  const float* W1 = (const float*)d_in[12]; const float* b1 = (const float*)d_in[13];
  const float* W2 = (const float*)d_in[14]; const float* b2 = (const float*)d_in[15];
  const float* ln1g = (const float*)d_in[16]; const float* ln1b = (const float*)d_in[17];
  const float* ln2g = (const float*)d_in[18]; const float* ln2b = (const float*)d_in[19];
  const float* ml   = (const float*)d_in[20];
  const int*   mask = (const int*)d_in[21];
  float* out = (float*)d_out;

  char* w = (char*)d_ws;
  auto alloc = [&](size_t sz) { char* p = w; w += (sz + 255) & ~(size_t)255; return p; };
  const int MT = BB * SS;  // 8192 rows

  unsigned short* WqvT = (unsigned short*)alloc((size_t)2048 * 1024 * 2);  // [2048][1024]
  unsigned short* WkcT = (unsigned short*)alloc((size_t)1024 * 2048 * 2);  // [1024][2048]
  unsigned short* WoT  = (unsigned short*)alloc((size_t)DD * DD * 2);
  unsigned short* W1T  = (unsigned short*)alloc((size_t)DD * DFFN * 2);    // [DFFN][DD]
  unsigned short* W2T  = (unsigned short*)alloc((size_t)DFFN * DD * 2);    // [DD][DFFN]
  float* qvb = (float*)alloc(2048 * 4);
  float* kcbias = (float*)alloc(1024 * 4);
  unsigned long long* mbits = (unsigned long long*)alloc((size_t)BB * SS * 8 * 8);
  unsigned short* sg  = (unsigned short*)alloc((size_t)SS * SS * 2);
  unsigned short* xt2 = (unsigned short*)alloc((size_t)MT * 2048 * 2);  // [xn | time]
  unsigned short* qbuf = (unsigned short*)alloc((size_t)MT * DD * 2);   // q [8192][1024]
  unsigned short* vTb = (unsigned short*)alloc((size_t)DD * MT * 2);    // v^T [1024][8192]
  unsigned short* kcb = (unsigned short*)alloc((size_t)MT * DD * 2);    // k1+k2
  float*          x2  = (float*)alloc((size_t)MT * DD * 4);
  unsigned short* hb  = (unsigned short*)alloc((size_t)MT * DFFN * 2);
  unsigned short* ctx = xt2;          // xt2 dead after qv+kc GEMMs
  unsigned short* xn2 = xt2;          // ctx dead after Wo GEMM

  // weight prep
  transpose_cvt<<<dim3(32, 32), 256, 0, stream>>>(Wq, WqvT, 1024, 1024);
  transpose_cvt<<<dim3(32, 32), 256, 0, stream>>>(Wv, WqvT + (size_t)1024 * 1024, 1024, 1024);
  transpose_cvt<<<dim3(32, 32), 256, 0, stream>>>(Wk, WkcT, 1024, 2048);
  transpose_cvt<<<dim3(32, 32), 256, 0, stream>>>(Wt, WkcT + 1024, 1024, 2048);
  transpose_cvt<<<dim3(32, 32), 256, 0, stream>>>(Wo, WoT, 1024, 1024);
  transpose_cvt<<<dim3(128, 32), 256, 0, stream>>>(W1, W1T, 4096, 1024);
  transpose_cvt<<<dim3(32, 128), 256, 0, stream>>>(W2, W2T, 1024, 4096);
  bias_prep<<<dim3(12), 256, 0, stream>>>(bq, bv, bk, bt, qvb, kcbias);
  mask_pack<<<dim3(BB * SS * SS / 256), 256, 0, stream>>>(mask, mbits);
  sig_cvt<<<dim3(SS * SS / 8 / 256), 256, 0, stream>>>(ml, sg);

  // xt2 = [ln1(x) | bf16(time)]
  ln_kernel<<<dim3(MT), 256, 0, stream>>>(x, ln1g, ln1b, xt2, 2048);
  cvt_bf16<<<dim3(MT * DD / 8 / 256), 256, 0, stream>>>(timep, xt2 + 1024, 2048);

  // projections: qv (N=2048,K=1024, q->qbuf, v->vT) ; kc (N=1024,K=2048)
  gemm8p<256, 3><<<dim3(256), 512, 0, stream>>>(xt2, 2048, WqvT, qvb, nullptr, (void*)qbuf, vTb, MT, 2048, 1024);
  gemm8p<128, 0><<<dim3(256), 512, 0, stream>>>(xt2, 2048, WkcT, kcbias, nullptr, (void*)kcb, nullptr, MT, 1024, 2048);

  attn3<<<dim3(BB * HH * 16), 256, 0, stream>>>(qbuf, vTb, kcb, mbits, sg, ctx);

  gemm8p<128, 1><<<dim3(256), 512, 0, stream>>>(ctx, 1024, WoT, bo, x, (void*)x2, nullptr, MT, 1024, 1024);
  ln_kernel<<<dim3(MT), 256, 0, stream>>>(x2, ln2g, ln2b, xn2, 1024);
  gemm8p<256, 2><<<dim3(512), 512, 0, stream>>>(xn2, 1024, W1T, b1, nullptr, (void*)hb, nullptr, MT, 4096, 1024);
  gemm8p<128, 1><<<dim3(256), 512, 0, stream>>>(hb, 4096, W2T, b2, x2, (void*)out, nullptr, MT, 1024, 4096);
}

// Round 6
// 499.110 us; speedup vs baseline: 1.5845x; 1.0731x over previous
//
#include <hip/hip_runtime.h>

#define BB   16
#define SS   512
#define DD   1024
#define HH   16
#define DKK  64
#define DFFN 4096
#define LN_EPS 1e-6f
#define QSCALE 0.18033688011112042f   // 0.125 * log2(e)

typedef __attribute__((ext_vector_type(8))) __bf16 bf16x8;
typedef __attribute__((ext_vector_type(4))) float f32x4;
typedef __attribute__((ext_vector_type(8))) unsigned short ushort8;
typedef __attribute__((ext_vector_type(4))) unsigned short ushort4_t;

#define AS1 __attribute__((address_space(1)))
#define AS3 __attribute__((address_space(3)))

__device__ __forceinline__ unsigned short f2bf(float f) {
  unsigned int u = __float_as_uint(f);
  u += 0x7FFFu + ((u >> 16) & 1u);   // round-nearest-even
  return (unsigned short)(u >> 16);
}
__device__ __forceinline__ float bf2f(unsigned short u) {
  return __uint_as_float(((unsigned int)u) << 16);
}

__device__ __forceinline__ float gelu_f(float x) {
  float x3 = x * x * x;
  return 0.5f * x * (1.0f + tanhf(0.7978845608028654f * (x + 0.044715f * x3)));
}

__device__ __forceinline__ void sbar() {
  __builtin_amdgcn_sched_barrier(0);
  __builtin_amdgcn_s_barrier();
  __builtin_amdgcn_sched_barrier(0);
}
#define WAITVM(N)                                         \
  do {                                                    \
    __builtin_amdgcn_sched_barrier(0);                    \
    asm volatile("s_waitcnt vmcnt(" #N ")" ::: "memory"); \
    __builtin_amdgcn_sched_barrier(0);                    \
  } while (0)

// ---------------- LayerNorm: fp32 in -> bf16 out (strided out)
__global__ __launch_bounds__(256) void ln_kernel(const float* __restrict__ x,
                                                 const float* __restrict__ g,
                                                 const float* __restrict__ b,
                                                 unsigned short* __restrict__ out, int ldo) {
  const int row = blockIdx.x;
  const int tid = threadIdx.x;
  const float* xr = x + (size_t)row * DD;
  float4 v = *(const float4*)(xr + tid * 4);
  float s = v.x + v.y + v.z + v.w;
#pragma unroll
  for (int off = 1; off < 64; off <<= 1) s += __shfl_xor(s, off);
  __shared__ float red[8];
  const int wid = tid >> 6, l = tid & 63;
  if (l == 0) red[wid] = s;
  __syncthreads();
  const float mean = (red[0] + red[1] + red[2] + red[3]) * (1.0f / DD);
  float4 d;
  d.x = v.x - mean; d.y = v.y - mean; d.z = v.z - mean; d.w = v.w - mean;
  float ss = d.x * d.x + d.y * d.y + d.z * d.z + d.w * d.w;
#pragma unroll
  for (int off = 1; off < 64; off <<= 1) ss += __shfl_xor(ss, off);
  if (l == 0) red[4 + wid] = ss;
  __syncthreads();
  const float var = (red[4] + red[5] + red[6] + red[7]) * (1.0f / (DD - 1));
  const float scale = 1.0f / (sqrtf(var) + LN_EPS);
  float4 gv = *(const float4*)(g + tid * 4);
  float4 bv = *(const float4*)(b + tid * 4);
  ushort4_t o;
  o[0] = f2bf(gv.x * d.x * scale + bv.x);
  o[1] = f2bf(gv.y * d.y * scale + bv.y);
  o[2] = f2bf(gv.z * d.z * scale + bv.z);
  o[3] = f2bf(gv.w * d.w * scale + bv.w);
  *(ushort4_t*)(out + (size_t)row * ldo + tid * 4) = o;
}

// ---------------- fp32 -> bf16, strided rows of DD elems
__global__ __launch_bounds__(256) void cvt_bf16(const float* __restrict__ in,
                                                unsigned short* __restrict__ out, int ldo) {
  const int i = blockIdx.x * 256 + threadIdx.x;  // i over MT*DD/8
  const int row = i >> 7;
  const int c0 = (i & 127) * 8;
  const float4* p = (const float4*)(in + (size_t)row * DD + c0);
  float4 a = p[0], b = p[1];
  ushort8 o;
  o[0] = f2bf(a.x); o[1] = f2bf(a.y); o[2] = f2bf(a.z); o[3] = f2bf(a.w);
  o[4] = f2bf(b.x); o[5] = f2bf(b.y); o[6] = f2bf(b.z); o[7] = f2bf(b.w);
  *(ushort8*)(out + (size_t)row * ldo + c0) = o;
}

// ---------------- W[K][N] fp32 -> WT[N][K] bf16 (strided out rows)
__global__ __launch_bounds__(256) void transpose_cvt(const float* __restrict__ W,
                                                     unsigned short* __restrict__ WT,
                                                     int N, int ldo) {
  __shared__ float tile[32][33];
  const int tx = threadIdx.x & 31, ty = threadIdx.x >> 5;  // ty 0..7
  const int n0 = blockIdx.x * 32, k0 = blockIdx.y * 32;
#pragma unroll
  for (int i = 0; i < 32; i += 8)
    tile[ty + i][tx] = W[(size_t)(k0 + ty + i) * N + n0 + tx];
  __syncthreads();
#pragma unroll
  for (int i = 0; i < 32; i += 8)
    WT[(size_t)(n0 + ty + i) * ldo + k0 + tx] = f2bf(tile[tx][ty + i]);
}

// ---------------- bias prep: qvb = concat(bq,bv) ; kcb = bk+bt
__global__ __launch_bounds__(256) void bias_prep(const float* __restrict__ bq,
                                                 const float* __restrict__ bv,
                                                 const float* __restrict__ bk,
                                                 const float* __restrict__ bt,
                                                 float* __restrict__ qvb,
                                                 float* __restrict__ kcb) {
  const int i = blockIdx.x * 256 + threadIdx.x;
  if (i < 2048) qvb[i] = (i < 1024) ? bq[i] : bv[i - 1024];
  else kcb[i - 2048] = bk[i - 2048] + bt[i - 2048];
}

// ---------------- gate[b][r][k] = mask ? sigmoid(ml[r][k]) : 0   (bf16)
__global__ __launch_bounds__(256) void gate_build(const int* __restrict__ mask,
                                                  const float* __restrict__ ml,
                                                  unsigned short* __restrict__ gate) {
  const int i = blockIdx.x * 256 + threadIdx.x;  // 8 elems/thread over B*S*S
  const size_t base = (size_t)i * 8;
  const int off = (int)(base & (SS * SS - 1));
  const int4* mp = (const int4*)(mask + base);
  const int4 m0 = mp[0], m1 = mp[1];
  const float4* lp = (const float4*)(ml + off);
  const float4 a = lp[0], b = lp[1];
  ushort8 o;
  o[0] = m0.x ? f2bf(1.0f / (1.0f + __expf(-a.x))) : 0;
  o[1] = m0.y ? f2bf(1.0f / (1.0f + __expf(-a.y))) : 0;
  o[2] = m0.z ? f2bf(1.0f / (1.0f + __expf(-a.z))) : 0;
  o[3] = m0.w ? f2bf(1.0f / (1.0f + __expf(-a.w))) : 0;
  o[4] = m1.x ? f2bf(1.0f / (1.0f + __expf(-b.x))) : 0;
  o[5] = m1.y ? f2bf(1.0f / (1.0f + __expf(-b.y))) : 0;
  o[6] = m1.z ? f2bf(1.0f / (1.0f + __expf(-b.z))) : 0;
  o[7] = m1.w ? f2bf(1.0f / (1.0f + __expf(-b.w))) : 0;
  *(ushort8*)(gate + base) = o;
}

// ---------------- 8-phase pipelined GEMM (unchanged from round 5, + q prescale)
template <int BM, int EPI>
__global__ __launch_bounds__(512, 2) void gemm8p(const unsigned short* __restrict__ A, int lda,
                                                 const unsigned short* __restrict__ BT,
                                                 const float* __restrict__ bias,
                                                 const float* __restrict__ resid,
                                                 void* __restrict__ Cout,
                                                 unsigned short* __restrict__ vTo,
                                                 int M, int N, int K) {
  constexpr int MI = BM / 32;
  constexpr int ASUB = BM / 16;
  constexpr int AHALF = BM * 32;
  constexpr int ABUF = BM * 64;
  constexpr int ACALL = BM / 128;

  __shared__ __align__(16) unsigned short smA[2 * ABUF];
  __shared__ __align__(16) unsigned short smB[2 * 16384];

  const int tid = threadIdx.x;
  const int w = tid >> 6, lane = tid & 63;
  const int lr = lane & 15, lg = lane >> 4;
  const int wr = w >> 2, wn = w & 3;

  const int nb = N / 256;
  const int nwg = gridDim.x;
  int bid = blockIdx.x;
  bid = (bid & 7) * (nwg >> 3) + (bid >> 3);
  const int mb = bid / nb, nbk = bid % nb;

  const int uo = (lane * 16) ^ (lane & 32);
  const int srow = uo >> 6;
  const int scol = (uo & 63) >> 1;

  const unsigned short* pA[2];
  const unsigned short* pB[2];
#pragma unroll
  for (int j = 0; j < ACALL; ++j)
    pA[j] = A + (size_t)(mb * BM + (j * 8 + w) * 16 + srow) * lda + scol;
  if (ACALL == 1) pA[1] = pA[0];
#pragma unroll
  for (int j = 0; j < 2; ++j)
    pB[j] = BT + (size_t)(nbk * 256 + (j * 8 + w) * 16 + srow) * K + scol;

  auto stA = [&](int kt, int ks, int j, int d) {
    __builtin_amdgcn_global_load_lds(
        (const AS1 void*)(pA[j] + (size_t)kt * 64 + ks * 32),
        (AS3 void*)(smA + d * ABUF + ks * AHALF + j * 4096 + w * 512), 16, 0, 0);
  };
  auto stB = [&](int kt, int ks, int j, int d) {
    __builtin_amdgcn_global_load_lds(
        (const AS1 void*)(pB[j] + (size_t)kt * 64 + ks * 32),
        (AS3 void*)(smB + d * 16384 + ks * 8192 + j * 4096 + w * 512), 16, 0, 0);
  };

  const int aoff = lr * 32 + ((lg * 8) ^ ((lr & 8) << 1));

  f32x4 acc[MI][4] = {};
  const int NT = K >> 6;

#pragma unroll
  for (int j = 0; j < ACALL; ++j) stA(0, 0, j, 0);
  stB(0, 0, 0, 0); stB(0, 0, 1, 0);
#pragma unroll
  for (int j = 0; j < ACALL; ++j) stA(0, 1, j, 0);
  stB(0, 1, 0, 0); stB(0, 1, 1, 0);
  if constexpr (ACALL == 2) { WAITVM(4); } else { WAITVM(3); }
  sbar();

  for (int kt = 0; kt < NT; ++kt) {
    const unsigned short* aD = smA + (kt & 1) * ABUF;
    const unsigned short* bD = smB + (kt & 1) * 16384;
    const int dn = (kt & 1) ^ 1;
    const bool nx = (kt + 1 < NT);
    bf16x8 af[4], bf[4];

#pragma unroll
    for (int i = 0; i < 4; ++i)
      bf[i] = *(const bf16x8*)(bD + (wn * 4 + i) * 512 + aoff);
#pragma unroll
    for (int i = 0; i < 4; ++i)
      af[i] = *(const bf16x8*)(aD + (wr * MI + i) * 512 + aoff);
    if (nx) {
#pragma unroll
      for (int j = 0; j < ACALL; ++j) stA(kt + 1, 0, j, dn);
      if constexpr (ACALL == 1) { stB(kt + 1, 0, 0, dn); stB(kt + 1, 0, 1, dn); }
    }
    if constexpr (ACALL == 1) { WAITVM(3); }
    sbar();
    __builtin_amdgcn_s_setprio(1);
#pragma unroll
    for (int mi = 0; mi < 4; ++mi)
#pragma unroll
      for (int ni = 0; ni < 4; ++ni)
        acc[mi][ni] = __builtin_amdgcn_mfma_f32_16x16x32_bf16(af[mi], bf[ni], acc[mi][ni], 0, 0, 0);
    __builtin_amdgcn_s_setprio(0);
    sbar();

    if constexpr (ACALL == 2) {
#pragma unroll
      for (int i = 0; i < 4; ++i)
        af[i] = *(const bf16x8*)(aD + (wr * MI + 4 + i) * 512 + aoff);
      if (nx) { stB(kt + 1, 0, 0, dn); stB(kt + 1, 0, 1, dn); }
      WAITVM(4);
      sbar();
      __builtin_amdgcn_s_setprio(1);
#pragma unroll
      for (int mi = 0; mi < 4; ++mi)
#pragma unroll
        for (int ni = 0; ni < 4; ++ni)
          acc[4 + mi][ni] = __builtin_amdgcn_mfma_f32_16x16x32_bf16(af[mi], bf[ni], acc[4 + mi][ni], 0, 0, 0);
      __builtin_amdgcn_s_setprio(0);
      sbar();
    }

#pragma unroll
    for (int i = 0; i < 4; ++i)
      bf[i] = *(const bf16x8*)(bD + (16 + wn * 4 + i) * 512 + aoff);
#pragma unroll
    for (int i = 0; i < 4; ++i)
      af[i] = *(const bf16x8*)(aD + (ASUB + wr * MI + i) * 512 + aoff);
    if (nx) {
#pragma unroll
      for (int j = 0; j < ACALL; ++j) stA(kt + 1, 1, j, dn);
      if constexpr (ACALL == 1) { stB(kt + 1, 1, 0, dn); stB(kt + 1, 1, 1, dn); }
    }
    if constexpr (ACALL == 1) { WAITVM(3); }
    sbar();
    __builtin_amdgcn_s_setprio(1);
#pragma unroll
    for (int mi = 0; mi < 4; ++mi)
#pragma unroll
      for (int ni = 0; ni < 4; ++ni)
        acc[mi][ni] = __builtin_amdgcn_mfma_f32_16x16x32_bf16(af[mi], bf[ni], acc[mi][ni], 0, 0, 0);
    __builtin_amdgcn_s_setprio(0);
    sbar();

    if constexpr (ACALL == 2) {
#pragma unroll
      for (int i = 0; i < 4; ++i)
        af[i] = *(const bf16x8*)(aD + (ASUB + wr * MI + 4 + i) * 512 + aoff);
      if (nx) { stB(kt + 1, 1, 0, dn); stB(kt + 1, 1, 1, dn); }
      WAITVM(4);
      sbar();
      __builtin_amdgcn_s_setprio(1);
#pragma unroll
      for (int mi = 0; mi < 4; ++mi)
#pragma unroll
        for (int ni = 0; ni < 4; ++ni)
          acc[4 + mi][ni] = __builtin_amdgcn_mfma_f32_16x16x32_bf16(af[mi], bf[ni], acc[4 + mi][ni], 0, 0, 0);
      __builtin_amdgcn_s_setprio(0);
      sbar();
    }
  }

  const int colb = nbk * 256 + wn * 64;
  const int rowb = mb * BM + wr * (BM / 2);
#pragma unroll
  for (int ni = 0; ni < 4; ++ni) {
    const int col = colb + ni * 16 + lr;
    const float bv = bias[col];
    if (EPI == 3 && (colb + ni * 16) >= 1024) {
#pragma unroll
      for (int mi = 0; mi < MI; ++mi) {
        const int row0 = rowb + mi * 16 + lg * 4;
        ushort4_t t;
#pragma unroll
        for (int j = 0; j < 4; ++j) t[j] = f2bf(acc[mi][ni][j] + bv);
        *(ushort4_t*)(vTo + (size_t)(col - 1024) * 8192 + row0) = t;
      }
    } else {
#pragma unroll
      for (int mi = 0; mi < MI; ++mi) {
#pragma unroll
        for (int j = 0; j < 4; ++j) {
          const int row = rowb + mi * 16 + lg * 4 + j;
          float vv = acc[mi][ni][j] + bv;
          if (EPI == 2) vv = gelu_f(vv);
          if (EPI == 1) {
            const size_t o = (size_t)row * N + col;
            ((float*)Cout)[o] = vv + resid[o];
          } else if (EPI == 3) {
            ((unsigned short*)Cout)[(size_t)row * 1024 + col] = f2bf(vv * QSCALE);
          } else {
            ((unsigned short*)Cout)[(size_t)row * N + col] = f2bf(vv);
          }
        }
      }
    }
  }
}

// ---------------- Fused attention v5: wave-private, barrier-free main loop.
// Block = (b,h,qt32), 4 waves; wave w owns keys [w*128, w*128+128).
// Per 32-key chunk: QK^T (q prescaled by 0.125*log2e) -> exp2 -> *gate ->
// wave-private padded LDS P -> PV partial ctx. End: 2 barriers, LDS reduce.
__global__ __launch_bounds__(256) void attn4(const unsigned short* __restrict__ qb,
                                             const unsigned short* __restrict__ vT,
                                             const unsigned short* __restrict__ kcb,
                                             const unsigned short* __restrict__ gate,
                                             unsigned short* __restrict__ ctx) {
  __shared__ __align__(16) unsigned char smem[33280];
  // phase 1: P buffers [wave][parity][32][40] u16 (20480 B)
  // phase 2 (after barrier): pctx [wave][32][64] f32 (32768 B)
  // sumw at +32768: [wave][32] f32 (512 B) -- disjoint from P region
  float* pctx = (float*)smem;
  float* sumw = (float*)(smem + 32768);

  const int tid = threadIdx.x;
  const int w = tid >> 6, l = tid & 63;
  const int lr = l & 15, lg = l >> 4;
  const int virt = (blockIdx.x & 7) * 512 + (blockIdx.x >> 3);
  const int qt = virt & 15;
  const int h = (virt >> 4) & 15;
  const int b = virt >> 8;
  const int q0 = qt * 32;

  const unsigned short* qg = qb + (size_t)b * SS * DD + h * DKK;
  const unsigned short* kg = kcb + (size_t)b * SS * DD + h * DKK;
  const unsigned short* vg = vT + (size_t)(h * DKK) * 8192 + b * SS;
  const unsigned short* gg = gate + (size_t)b * SS * SS;
  unsigned short* cg = ctx + (size_t)b * SS * DD + h * DKK;

  // Q A-frags (prescaled): rows q0+mi*16+lr, dk = ks*32+lg*8
  bf16x8 qf[2][2];
#pragma unroll
  for (int mi = 0; mi < 2; ++mi)
#pragma unroll
    for (int ks = 0; ks < 2; ++ks)
      qf[mi][ks] = *(const bf16x8*)(qg + (size_t)(q0 + mi * 16 + lr) * DD + ks * 32 + lg * 8);

  f32x4 acc[2][4] = {};   // [mi][dkg] partial ctx over own keys
  float ssum[2][4] = {};  // [mi][j] row-sum over own keys
  const int kb0 = w * 128;

#pragma unroll
  for (int it = 0; it < 4; ++it) {
    const int kbase = kb0 + it * 32;
    unsigned short* Pb = (unsigned short*)smem + w * 2560 + (it & 1) * 1280;  // [32][40]

    // QK^T: 8 MFMAs
    bf16x8 kf[2][2];
#pragma unroll
    for (int ni = 0; ni < 2; ++ni)
#pragma unroll
      for (int ks = 0; ks < 2; ++ks)
        kf[ni][ks] = *(const bf16x8*)(kg + (size_t)(kbase + ni * 16 + lr) * DD + ks * 32 + lg * 8);
    f32x4 sc[2][2] = {};
#pragma unroll
    for (int ks = 0; ks < 2; ++ks)
#pragma unroll
      for (int mi = 0; mi < 2; ++mi)
#pragma unroll
        for (int ni = 0; ni < 2; ++ni)
          sc[mi][ni] = __builtin_amdgcn_mfma_f32_16x16x32_bf16(qf[mi][ks], kf[ni][ks], sc[mi][ni], 0, 0, 0);

    // V B-frags for this chunk (independent of P, hides under softmax)
    bf16x8 vb[4];
#pragma unroll
    for (int dkg = 0; dkg < 4; ++dkg)
      vb[dkg] = *(const bf16x8*)(vg + (size_t)(dkg * 16 + lr) * 8192 + kbase + lg * 8);

    // softmax numerator + gated write to wave-private P
#pragma unroll
    for (int mi = 0; mi < 2; ++mi)
#pragma unroll
      for (int ni = 0; ni < 2; ++ni)
#pragma unroll
        for (int j = 0; j < 4; ++j) {
          const int row = mi * 16 + lg * 4 + j;
          const unsigned short gu = gg[(size_t)(q0 + row) * SS + kbase + ni * 16 + lr];
          const float e = exp2f(sc[mi][ni][j]);
          ssum[mi][j] += gu ? e : 0.0f;
          Pb[row * 40 + ni * 16 + lr] = f2bf(e * bf2f(gu));
        }

    // PV: 8 MFMAs (same-wave lgkmcnt orders P write->read; no barrier)
#pragma unroll
    for (int mi = 0; mi < 2; ++mi) {
      const bf16x8 pa = *(const bf16x8*)(Pb + (mi * 16 + lr) * 40 + lg * 8);
#pragma unroll
      for (int dkg = 0; dkg < 4; ++dkg)
        acc[mi][dkg] = __builtin_amdgcn_mfma_f32_16x16x32_bf16(pa, vb[dkg], acc[mi][dkg], 0, 0, 0);
    }
  }

  // row-sum partials -> sumw (region disjoint from P; safe pre-barrier)
#pragma unroll
  for (int mi = 0; mi < 2; ++mi)
#pragma unroll
    for (int j = 0; j < 4; ++j) {
      float s = ssum[mi][j];
      s += __shfl_xor(s, 1);
      s += __shfl_xor(s, 2);
      s += __shfl_xor(s, 4);
      s += __shfl_xor(s, 8);
      if (lr == 0) sumw[w * 32 + mi * 16 + lg * 4 + j] = s;
    }
  __syncthreads();  // all P reads done -> safe to overlay pctx

  // partial ctx -> LDS
#pragma unroll
  for (int mi = 0; mi < 2; ++mi)
#pragma unroll
    for (int dkg = 0; dkg < 4; ++dkg)
#pragma unroll
      for (int j = 0; j < 4; ++j)
        pctx[(size_t)w * 2048 + (mi * 16 + lg * 4 + j) * 64 + dkg * 16 + lr] = acc[mi][dkg][j];
  __syncthreads();

  // final: thread t -> (row = t>>3, dk0 = (t&7)*8)
  {
    const int row = tid >> 3;
    const int dk0 = (tid & 7) * 8;
    const float tot = sumw[row] + sumw[32 + row] + sumw[64 + row] + sumw[96 + row];
    const float inv = 1.0f / fmaxf(tot, 1e-30f);
    float vsum[8];
#pragma unroll
    for (int c = 0; c < 8; ++c) vsum[c] = 0.0f;
#pragma unroll
    for (int ww = 0; ww < 4; ++ww) {
      const float* p = pctx + (size_t)ww * 2048 + row * 64 + dk0;
      f32x4 a = *(const f32x4*)p;
      f32x4 bq = *(const f32x4*)(p + 4);
#pragma unroll
      for (int c = 0; c < 4; ++c) { vsum[c] += a[c]; vsum[4 + c] += bq[c]; }
    }
    ushort8 o;
#pragma unroll
    for (int c = 0; c < 8; ++c) o[c] = f2bf(vsum[c] * inv);
    *(ushort8*)(cg + (size_t)(q0 + row) * DD + dk0) = o;
  }
}

// ----------------------------------------------------------------------------
extern "C" void kernel_launch(void* const* d_in, const int* in_sizes, int n_in,
                              void* d_out, int out_size, void* d_ws, size_t ws_size,
                              hipStream_t stream) {
  (void)in_sizes; (void)n_in; (void)out_size; (void)ws_size;
  const float* x    = (const float*)d_in[0];
  const float* timep= (const float*)d_in[1];
  const float* Wq = (const float*)d_in[2];  const float* bq = (const float*)d_in[3];
  const float* Wk = (const float*)d_in[4];  const float* bk = (const float*)d_in[5];
  const float* Wt = (const float*)d_in[6];  const float* bt = (const float*)d_in[7];
  const float* Wv = (const float*)d_in[8];  const float* bv = (const float*)d_in[9];
  const float* Wo = (const float*)d_in[10]; const float* bo = (const float*)d_in[11];
  const float* W1 = (const float*)d_in[12]; const float* b1 = (const float*)d_in[13];
  const float* W2 = (const float*)d_in[14]; const float* b2 = (const float*)d_in[15];
  const float* ln1g = (const float*)d_in[16]; const float* ln1b = (const float*)d_in[17];
  const float* ln2g = (const float*)d_in[18]; const float* ln2b = (const float*)d_in[19];
  const float* ml   = (const float*)d_in[20];
  const int*   mask = (const int*)d_in[21];
  float* out = (float*)d_out;

  char* w = (char*)d_ws;
  auto alloc = [&](size_t sz) { char* p = w; w += (sz + 255) & ~(size_t)255; return p; };
  const int MT = BB * SS;  // 8192 rows

  unsigned short* WqvT = (unsigned short*)alloc((size_t)2048 * 1024 * 2);  // [2048][1024]
  unsigned short* WkcT = (unsigned short*)alloc((size_t)1024 * 2048 * 2);  // [1024][2048]
  unsigned short* WoT  = (unsigned short*)alloc((size_t)DD * DD * 2);
  unsigned short* W1T  = (unsigned short*)alloc((size_t)DD * DFFN * 2);    // [DFFN][DD]
  unsigned short* W2T  = (unsigned short*)alloc((size_t)DFFN * DD * 2);    // [DD][DFFN]
  float* qvb = (float*)alloc(2048 * 4);
  float* kcbias = (float*)alloc(1024 * 4);
  unsigned short* gateb = (unsigned short*)alloc((size_t)BB * SS * SS * 2);
  unsigned short* xt2 = (unsigned short*)alloc((size_t)MT * 2048 * 2);  // [xn | time]
  unsigned short* qbuf = (unsigned short*)alloc((size_t)MT * DD * 2);   // q [8192][1024] (prescaled)
  unsigned short* vTb = (unsigned short*)alloc((size_t)DD * MT * 2);    // v^T [1024][8192]
  unsigned short* kcb = (unsigned short*)alloc((size_t)MT * DD * 2);    // k1+k2
  float*          x2  = (float*)alloc((size_t)MT * DD * 4);
  unsigned short* hb  = (unsigned short*)alloc((size_t)MT * DFFN * 2);
  unsigned short* ctx = xt2;          // xt2 dead after qv+kc GEMMs
  unsigned short* xn2 = xt2;          // ctx dead after Wo GEMM

  // weight prep
  transpose_cvt<<<dim3(32, 32), 256, 0, stream>>>(Wq, WqvT, 1024, 1024);
  transpose_cvt<<<dim3(32, 32), 256, 0, stream>>>(Wv, WqvT + (size_t)1024 * 1024, 1024, 1024);
  transpose_cvt<<<dim3(32, 32), 256, 0, stream>>>(Wk, WkcT, 1024, 2048);
  transpose_cvt<<<dim3(32, 32), 256, 0, stream>>>(Wt, WkcT + 1024, 1024, 2048);
  transpose_cvt<<<dim3(32, 32), 256, 0, stream>>>(Wo, WoT, 1024, 1024);
  transpose_cvt<<<dim3(128, 32), 256, 0, stream>>>(W1, W1T, 4096, 1024);
  transpose_cvt<<<dim3(32, 128), 256, 0, stream>>>(W2, W2T, 1024, 4096);
  bias_prep<<<dim3(12), 256, 0, stream>>>(bq, bv, bk, bt, qvb, kcbias);
  gate_build<<<dim3(BB * SS * SS / 8 / 256), 256, 0, stream>>>(mask, ml, gateb);

  // xt2 = [ln1(x) | bf16(time)]
  ln_kernel<<<dim3(MT), 256, 0, stream>>>(x, ln1g, ln1b, xt2, 2048);
  cvt_bf16<<<dim3(MT * DD / 8 / 256), 256, 0, stream>>>(timep, xt2 + 1024, 2048);

  // projections: qv (N=2048,K=1024, q->qbuf prescaled, v->vT) ; kc (N=1024,K=2048)
  gemm8p<256, 3><<<dim3(256), 512, 0, stream>>>(xt2, 2048, WqvT, qvb, nullptr, (void*)qbuf, vTb, MT, 2048, 1024);
  gemm8p<128, 0><<<dim3(256), 512, 0, stream>>>(xt2, 2048, WkcT, kcbias, nullptr, (void*)kcb, nullptr, MT, 1024, 2048);

  attn4<<<dim3(BB * HH * 16), 256, 0, stream>>>(qbuf, vTb, kcb, gateb, ctx);

  gemm8p<128, 1><<<dim3(256), 512, 0, stream>>>(ctx, 1024, WoT, bo, x, (void*)x2, nullptr, MT, 1024, 1024);
  ln_kernel<<<dim3(MT), 256, 0, stream>>>(x2, ln2g, ln2b, xn2, 1024);
  gemm8p<256, 2><<<dim3(512), 512, 0, stream>>>(xn2, 1024, W1T, b1, nullptr, (void*)hb, nullptr, MT, 4096, 1024);
  gemm8p<128, 1><<<dim3(256), 512, 0, stream>>>(hb, 4096, W2T, b2, x2, (void*)out, nullptr, MT, 1024, 4096);
}